// Round 4
// baseline (537.940 us; speedup 1.0000x reference)
//
#include <hip/hip_runtime.h>
#include <hip/hip_bf16.h>
#include <math.h>

typedef __attribute__((ext_vector_type(8))) short bf16x8;   // 8 bf16 in 4 VGPRs
typedef __attribute__((ext_vector_type(4))) float f32x4;    // MFMA C/D frag
typedef unsigned short ushort_t;

__device__ __forceinline__ ushort_t f2bf(float f) {
    union { float f; unsigned u; } v; v.f = f;
    unsigned r = v.u + 0x7FFF + ((v.u >> 16) & 1);   // RNE
    return (ushort_t)(r >> 16);
}

// pack two f32 -> 2 bf16 (round-half-up): 2 adds + 1 v_perm; a in low half
__device__ __forceinline__ unsigned pack2bf(float a, float b) {
    union { float f; unsigned u; } x, y; x.f = a; y.f = b;
    return __builtin_amdgcn_perm(y.u + 0x8000u, x.u + 0x8000u, 0x07060302u);
}

// single-instruction pair pack (RNE), a in low half
__device__ __forceinline__ unsigned cvtpk2bf(float a, float b) {
    unsigned r;
    asm("v_cvt_pk_bf16_f32 %0, %1, %2" : "=v"(r) : "v"(a), "v"(b));
    return r;
}

// async 16B global -> LDS (wave-uniform LDS base; lane data lands at base+lane*16)
__device__ __forceinline__ void gl2lds(const void* g, void* l) {
    __builtin_amdgcn_global_load_lds(
        (const __attribute__((address_space(1))) void*)g,
        (__attribute__((address_space(3))) void*)l, 16, 0, 0);
}

// fast GELU (tanh form via sigmoid): max |err| vs erf-GELU ~1e-3
__device__ __forceinline__ float fast_gelu(float tt) {
    float t2 = tt * tt;
    float arg = tt * fmaf(0.07135481283f, t2, 1.595769122f);
    float e = __builtin_amdgcn_exp2f(arg * -1.442695041f);
    return tt * __builtin_amdgcn_rcpf(1.0f + e);
}

// ---------------------------------------------------------------------------
// Merged transpose+cast for all 4 weights (one launch).
// ---------------------------------------------------------------------------
__global__ __launch_bounds__(256)
void tcast_all(const float* __restrict__ wqkv, const float* __restrict__ wproj,
               const float* __restrict__ w1, const float* __restrict__ w2,
               ushort_t* __restrict__ wqkvT, ushort_t* __restrict__ wprojT,
               ushort_t* __restrict__ w1T, ushort_t* __restrict__ w2T,
               float qscale) {
    __shared__ float tile[32][33];
    int id = blockIdx.x;
    const float* in; ushort_t* out; int R, Cc, gx, scale_n;
    if (id < 3072)      { in = wqkv;  out = wqkvT;  R = 1024; Cc = 3072; gx = 96;  scale_n = 1024; }
    else if (id < 4096) { id -= 3072; in = wproj; out = wprojT; R = 1024; Cc = 1024; gx = 32; scale_n = 0; }
    else if (id < 8192) { id -= 4096; in = w1;    out = w1T;    R = 1024; Cc = 4096; gx = 128; scale_n = 0; }
    else                { id -= 8192; in = w2;    out = w2T;    R = 4096; Cc = 1024; gx = 32; scale_n = 0; }
    int bc = (id % gx) * 32, br = (id / gx) * 32;
    int tx = threadIdx.x, ty = threadIdx.y;
    #pragma unroll
    for (int i = 0; i < 32; i += 8)
        tile[ty + i][tx] = in[(size_t)(br + ty + i) * Cc + bc + tx];
    __syncthreads();
    #pragma unroll
    for (int i = 0; i < 32; i += 8) {
        int n = bc + ty + i;
        float v = tile[tx][ty + i];
        if (n < scale_n) v *= qscale;
        out[(size_t)n * R + br + tx] = f2bf(v);
    }
}

// ---------------------------------------------------------------------------
// LayerNorm over rows of 1024, fp32 in -> bf16 out. One block (256) per row.
// ---------------------------------------------------------------------------
__global__ __launch_bounds__(256)
void ln_kernel(const float* __restrict__ x, const float* __restrict__ g,
               const float* __restrict__ b, ushort_t* __restrict__ out) {
    const int row = blockIdx.x;
    const int t = threadIdx.x;
    const float4 xv = ((const float4*)(x + (size_t)row * 1024))[t];
    float s  = xv.x + xv.y + xv.z + xv.w;
    float ss = xv.x*xv.x + xv.y*xv.y + xv.z*xv.z + xv.w*xv.w;
    #pragma unroll
    for (int off = 32; off > 0; off >>= 1) {
        s  += __shfl_xor(s, off);
        ss += __shfl_xor(ss, off);
    }
    __shared__ float red[8];
    int wave = t >> 6, lane = t & 63;
    if (lane == 0) { red[wave] = s; red[4 + wave] = ss; }
    __syncthreads();
    s  = red[0] + red[1] + red[2] + red[3];
    ss = red[4] + red[5] + red[6] + red[7];
    float mu  = s * (1.0f / 1024.0f);
    float var = ss * (1.0f / 1024.0f) - mu * mu;
    float rstd = rsqrtf(var + 1e-5f);
    float4 gv = ((const float4*)g)[t];
    float4 bv = ((const float4*)b)[t];
    ushort4 o;
    o.x = f2bf((xv.x - mu) * rstd * gv.x + bv.x);
    o.y = f2bf((xv.y - mu) * rstd * gv.y + bv.y);
    o.z = f2bf((xv.z - mu) * rstd * gv.z + bv.z);
    o.w = f2bf((xv.w - mu) * rstd * gv.w + bv.w);
    ((ushort4*)(out + (size_t)row * 1024))[t] = o;
}

// ---------------------------------------------------------------------------
// GEMM 256x128, BK=64, 8 waves (4M x 2N), 3-buffer LDS ring (144 KB), counted
// vmcnt pipeline: iter t issues tile t+2's 6 loads, waits vmcnt(12) (= only
// tile t's loads; t+1/t+2 stay in flight with >= 2 K-tiles of compute cover),
// raw s_barrier, 32 MFMA with setprio, s_barrier. vmcnt never drains to 0 in
// the main loop (T4). XOR chunk swizzle at global source; bijective XCD
// swizzle (all grids % 8 == 0).
// MODE 0: bf16 (n0>=2048 tiles also transposed to vTout when non-null)
// MODE 1: f32 = acc+res | 2: bf16 = gelu(acc+bias) | 3: f32 = acc+bias+res
// ---------------------------------------------------------------------------
template<int MODE, int K, int N>
__global__ __launch_bounds__(512, 2)
void gemm3b(const ushort_t* __restrict__ A, const ushort_t* __restrict__ Bt,
            void* __restrict__ Cout, const float* __restrict__ bias,
            const float* __restrict__ res, ushort_t* __restrict__ vTout) {
    constexpr int BK = 64;
    constexpr int NT = K / BK;
    __shared__ __align__(16) ushort_t As[3][256 * 64];   // 96 KB
    __shared__ __align__(16) ushort_t Bs[3][128 * 64];   // 48 KB
    const int tid = threadIdx.x;
    const int wave = tid >> 6, lane = tid & 63;
    const int quad = lane >> 4, l16 = lane & 15;
    // bijective XCD swizzle (nwg % 8 == 0 for all launched grids)
    const int nwg = gridDim.x * gridDim.y;
    int id = blockIdx.y * gridDim.x + blockIdx.x;
    id = (id & 7) * (nwg >> 3) + (id >> 3);
    const int m0 = (id / gridDim.x) * 256, n0 = (id % gridDim.x) * 128;
    const int wm = (wave >> 1) * 64, wn = (wave & 1) * 64;

    const int r0 = tid >> 3, pc = tid & 7;   // 512 thr: 64 rows x 8 chunks
    const int lc = pc ^ (r0 & 7);
    const ushort_t* aSrc = A  + (size_t)(m0 + r0) * K + lc * 8;
    const ushort_t* bSrc = Bt + (size_t)(n0 + r0) * K + lc * 8;
    const int swz = l16 & 7;

    f32x4 acc[4][4] = {};

    // stage tile tt into ring slot bb: 6 calls/wave (A rows 0..255, B rows 0..127)
    #define STAGE3(tt, bb) do { \
        const size_t ko = (size_t)(tt) * BK; \
        char* aD = (char*)&As[bb][0] + wave * 1024; \
        char* bD = (char*)&Bs[bb][0] + wave * 1024; \
        _Pragma("unroll") \
        for (int c = 0; c < 4; ++c) \
            gl2lds(aSrc + (size_t)c * 64 * K + ko, aD + c * 8192); \
        _Pragma("unroll") \
        for (int c = 0; c < 2; ++c) \
            gl2lds(bSrc + (size_t)c * 64 * K + ko, bD + c * 8192); \
    } while (0)

    STAGE3(0, 0);
    STAGE3(1, 1);

    for (int t = 0; t < NT; ++t) {
        const int cur = t % 3;
        if (t + 2 < NT) {
            STAGE3(t + 2, (t + 2) % 3);
            asm volatile("s_waitcnt vmcnt(12)" ::: "memory");   // tile t landed
        } else if (t + 1 < NT) {
            asm volatile("s_waitcnt vmcnt(6)" ::: "memory");    // tile t landed
        } else {
            asm volatile("s_waitcnt vmcnt(0)" ::: "memory");    // last tile
        }
        __builtin_amdgcn_s_barrier();   // all waves' loads for tile t visible
        const ushort_t* Ac = &As[cur][0];
        const ushort_t* Bc = &Bs[cur][0];
        #pragma unroll
        for (int ks = 0; ks < 2; ++ks) {
            const int cko = ((ks * 4 + quad) ^ swz) * 8;
            bf16x8 af[4], bfr[4];
            #pragma unroll
            for (int i = 0; i < 4; ++i)
                af[i] = *(const bf16x8*)(&Ac[(wm + i * 16 + l16) * 64 + cko]);
            #pragma unroll
            for (int j = 0; j < 4; ++j)
                bfr[j] = *(const bf16x8*)(&Bc[(wn + j * 16 + l16) * 64 + cko]);
            __builtin_amdgcn_s_setprio(1);
            #pragma unroll
            for (int i = 0; i < 4; ++i)
                #pragma unroll
                for (int j = 0; j < 4; ++j)
                    acc[i][j] = __builtin_amdgcn_mfma_f32_16x16x32_bf16(
                        af[i], bfr[j], acc[i][j], 0, 0, 0);
            __builtin_amdgcn_s_setprio(0);
        }
        __builtin_amdgcn_s_barrier();   // ring slot (t%3) free for tile t+3
    }
    #undef STAGE3

    // epilogue: C/D layout col = lane&15, row = quad*4 + reg
    if constexpr (MODE == 0) {
        if (vTout && n0 >= 2048) {
            #pragma unroll
            for (int i = 0; i < 4; ++i) {
                int m = m0 + wm + i * 16 + quad * 4;
                int bb = m >> 11, tq = m & 2047;
                #pragma unroll
                for (int j = 0; j < 4; ++j) {
                    int nn = n0 - 2048 + wn + j * 16 + l16;
                    int h = nn >> 6, d = nn & 63;
                    uint2 pk;
                    pk.x = pack2bf(acc[i][j][0], acc[i][j][1]);
                    pk.y = pack2bf(acc[i][j][2], acc[i][j][3]);
                    *(uint2*)(vTout + ((size_t)(bb * 16 + h) * 64 + d) * 2048 + tq) = pk;
                }
            }
            return;
        }
    }
    float bj[4];
    if constexpr (MODE == 2 || MODE == 3) {
        #pragma unroll
        for (int j = 0; j < 4; ++j) bj[j] = bias[n0 + wn + j * 16 + l16];
    }
    #pragma unroll
    for (int i = 0; i < 4; ++i) {
        #pragma unroll
        for (int j = 0; j < 4; ++j) {
            #pragma unroll
            for (int r = 0; r < 4; ++r) {
                int m = m0 + wm + i * 16 + quad * 4 + r;
                int n = n0 + wn + j * 16 + l16;
                size_t idx = (size_t)m * N + n;
                float v = acc[i][j][r];
                if constexpr (MODE == 0) {
                    ((ushort_t*)Cout)[idx] = f2bf(v);
                } else if constexpr (MODE == 1) {
                    ((float*)Cout)[idx] = v + res[idx];
                } else if constexpr (MODE == 2) {
                    ((ushort_t*)Cout)[idx] = f2bf(fast_gelu(v + bj[j]));
                } else {
                    ((float*)Cout)[idx] = v + bj[j] + res[idx];
                }
            }
        }
    }
}

// ---------------------------------------------------------------------------
// Flash attention, S^T formulation, no max-subtraction, double-buffered K/V,
// in-register P transpose via v_permlane{32,16}_swap_b32 (no P LDS round-trip).
// qkv bf16 [4,2048,3072] (Q pre-scaled by 0.125*log2e), vT [64bh][64d][2048t].
// Round-1 form (best measured 112 us): merged i-loop, cvt_pk pack, ones-MFMA
// row-sum for the softmax denominator, no setprio.
// ---------------------------------------------------------------------------
__global__ __launch_bounds__(256)
void attn_kernel(const ushort_t* __restrict__ qkv, const ushort_t* __restrict__ vT,
                 ushort_t* __restrict__ out) {
    constexpr int T = 2048, C3 = 3072, BQ = 128;
    __shared__ __align__(16) ushort_t Ks[2][64 * 64];   // [key][d], swizzled
    __shared__ __align__(16) ushort_t Vs[2][64 * 64];   // [d][key], swizzled
    const int bh = blockIdx.x, b = bh >> 4, h = bh & 15;
    const int qt = blockIdx.y;
    const int tid = threadIdx.x, wave = tid >> 6, lane = tid & 63;
    const int quad = lane >> 4, l16 = lane & 15;
    const int swz = l16 & 7;

    // Q B-frags in registers: lane l16 = q, i = q-block, ks = d-half
    bf16x8 qf[2][2];
    {
        const ushort_t* Qg = qkv + ((size_t)b * T + qt * BQ + wave * 32) * C3 + h * 64;
        #pragma unroll
        for (int i = 0; i < 2; ++i)
            #pragma unroll
            for (int ks = 0; ks < 2; ++ks)
                qf[i][ks] = *(const bf16x8*)(Qg + (size_t)(i * 16 + l16) * C3 + ks * 32 + quad * 8);
    }
    // all-ones frag: mfma(pf, ones) row-sums P on the matrix pipe
    bf16x8 onesf;
    #pragma unroll
    for (int e = 0; e < 8; ++e) onesf[e] = (short)0x3F80;   // bf16 1.0

    // staging sources (swizzled chunks)
    const int r0 = tid >> 3, pc = tid & 7;
    const int lc = pc ^ (r0 & 7);
    const ushort_t* KgB = qkv + (size_t)b * T * C3 + 1024 + h * 64 + (size_t)r0 * C3 + lc * 8;
    const ushort_t* VgB = vT + (size_t)bh * 64 * T + (size_t)r0 * T + lc * 8;
    char* kDst0 = (char*)&Ks[0][0] + wave * 1024;
    char* vDst0 = (char*)&Vs[0][0] + wave * 1024;

    f32x4 o_acc[2][4] = {};
    f32x4 l_acc[2] = {};   // row = quad*4+r (any col); accumulated via ones-MFMA

    // prologue: stage tile 0 into buffer 0
    #pragma unroll
    for (int c = 0; c < 2; ++c) {
        gl2lds(KgB + (size_t)c * 32 * C3, kDst0 + c * 4096);
        gl2lds(VgB + (size_t)c * 32 * T,  vDst0 + c * 4096);
    }

    for (int kt = 0; kt < T / 64; ++kt) {
        const int cur = kt & 1;
        __syncthreads();   // buf[cur] staged; buf[cur^1] readers (prev iter) done
        if (kt + 1 < T / 64) {
            const int nb = (cur ^ 1) * 8192;
            #pragma unroll
            for (int c = 0; c < 2; ++c) {
                gl2lds(KgB + ((size_t)(kt + 1) * 64 + c * 32) * C3, kDst0 + nb + c * 4096);
                gl2lds(VgB + (size_t)c * 32 * T + (kt + 1) * 64,    vDst0 + nb + c * 4096);
            }
        }
        const ushort_t* Kc = &Ks[cur][0];
        const ushort_t* Vc = &Vs[cur][0];

        // S^T = K * Q^T : D col = q = l16, row = key = j*16 + quad*4 + r
        f32x4 s[2][4] = {};
        #pragma unroll
        for (int ks = 0; ks < 2; ++ks) {
            const int cko = ((ks * 4 + quad) ^ swz) * 8;
            bf16x8 kf[4];
            #pragma unroll
            for (int j = 0; j < 4; ++j)
                kf[j] = *(const bf16x8*)(&Kc[(j * 16 + l16) * 64 + cko]);
            #pragma unroll
            for (int i = 0; i < 2; ++i)
                #pragma unroll
                for (int j = 0; j < 4; ++j)
                    s[i][j] = __builtin_amdgcn_mfma_f32_16x16x32_bf16(
                        kf[j], qf[i][ks], s[i][j], 0, 0, 0);
        }

        // p = 2^s, pack (v_cvt_pk_bf16_f32), transpose C-frag -> A-frag in regs.
        bf16x8 pf[2][2];
        #pragma unroll
        for (int i = 0; i < 2; ++i) {
            unsigned u[4][2];
            #pragma unroll
            for (int j = 0; j < 4; ++j) {
                float p0 = __builtin_amdgcn_exp2f(s[i][j][0]);
                float p1 = __builtin_amdgcn_exp2f(s[i][j][1]);
                float p2 = __builtin_amdgcn_exp2f(s[i][j][2]);
                float p3 = __builtin_amdgcn_exp2f(s[i][j][3]);
                u[j][0] = cvtpk2bf(p0, p1);
                u[j][1] = cvtpk2bf(p2, p3);
            }
            #pragma unroll
            for (int ks2 = 0; ks2 < 2; ++ks2) {
                unsigned d0 = u[2 * ks2][0], d2 = u[2 * ks2 + 1][0];
                asm("v_permlane32_swap_b32 %0, %1\n\t"
                    "v_permlane16_swap_b32 %0, %1" : "+v"(d0), "+v"(d2));
                unsigned d1 = u[2 * ks2][1], d3 = u[2 * ks2 + 1][1];
                asm("v_permlane32_swap_b32 %0, %1\n\t"
                    "v_permlane16_swap_b32 %0, %1" : "+v"(d1), "+v"(d3));
                union { unsigned d[4]; bf16x8 v; } fr;
                fr.d[0] = d0; fr.d[1] = d1; fr.d[2] = d2; fr.d[3] = d3;
                pf[i][ks2] = fr.v;
            }
        }

        // O += P V : A = pf (registers), B = Vs[d][key]; l += P * ones
        #pragma unroll
        for (int ks2 = 0; ks2 < 2; ++ks2) {
            const int cko = ((ks2 * 4 + quad) ^ swz) * 8;
            bf16x8 vf[4];
            #pragma unroll
            for (int j = 0; j < 4; ++j)
                vf[j] = *(const bf16x8*)(&Vc[(j * 16 + l16) * 64 + cko]);
            #pragma unroll
            for (int i = 0; i < 2; ++i) {
                #pragma unroll
                for (int j = 0; j < 4; ++j)
                    o_acc[i][j] = __builtin_amdgcn_mfma_f32_16x16x32_bf16(
                        pf[i][ks2], vf[j], o_acc[i][j], 0, 0, 0);
                l_acc[i] = __builtin_amdgcn_mfma_f32_16x16x32_bf16(
                    pf[i][ks2], onesf, l_acc[i], 0, 0, 0);
            }
        }
    }

    // normalize + store: l_acc[i][r] is the row sum for row quad*4+r (+16i)
    #pragma unroll
    for (int i = 0; i < 2; ++i) {
        #pragma unroll
        for (int r = 0; r < 4; ++r) {
            float inv = 1.0f / l_acc[i][r];
            int row = qt * BQ + wave * 32 + i * 16 + quad * 4 + r;
            size_t orow = ((size_t)b * T + row) * 1024 + h * 64;
            #pragma unroll
            for (int j = 0; j < 4; ++j)
                out[orow + j * 16 + l16] = f2bf(o_acc[i][j][r] * inv);
        }
    }
}

// ---------------------------------------------------------------------------
extern "C" void kernel_launch(void* const* d_in, const int* in_sizes, int n_in,
                              void* d_out, int out_size, void* d_ws, size_t ws_size,
                              hipStream_t stream) {
    const float* x     = (const float*)d_in[0];
    const float* ln1g  = (const float*)d_in[1];
    const float* ln1b  = (const float*)d_in[2];
    const float* ln2g  = (const float*)d_in[3];
    const float* ln2b  = (const float*)d_in[4];
    const float* wqkv  = (const float*)d_in[5];
    const float* wproj = (const float*)d_in[6];
    const float* w1    = (const float*)d_in[7];
    const float* b1    = (const float*)d_in[8];
    const float* w2    = (const float*)d_in[9];
    const float* b2    = (const float*)d_in[10];
    float* out = (float*)d_out;

    const size_t MT = 8192;  // B*T
    ushort_t* wqkvT  = (ushort_t*)d_ws;              // [3072][1024]
    ushort_t* wprojT = wqkvT  + (size_t)3072 * 1024; // [1024][1024]
    ushort_t* w1T    = wprojT + (size_t)1024 * 1024; // [4096][1024]
    ushort_t* w2T    = w1T    + (size_t)4096 * 1024; // [1024][4096]
    ushort_t* xn     = w2T    + (size_t)1024 * 4096; // [8192][1024] bf16
    ushort_t* qkvb   = xn     + MT * 1024;           // [8192][3072] bf16 (V part unused)
    ushort_t* attnb  = qkvb   + MT * 3072;           // [8192][1024] bf16
    float*    x2     = (float*)(attnb + MT * 1024);  // [8192][1024] f32
    ushort_t* xn2    = (ushort_t*)(x2 + MT * 1024);  // [8192][1024] bf16
    ushort_t* h1     = xn;                 // reuse xn+qkvb (both dead): [8192][4096]
    ushort_t* vT     = (ushort_t*)x2;      // reuse x2 region pre-proj: [64][64][2048]

    dim3 blk256(256);
    dim3 blk512(512);
    dim3 tblk(32, 8);
    const float qscale = 0.125f * 1.4426950408889634f;  // score scale * log2(e), folded into Q

    tcast_all<<<dim3(12288), tblk, 0, stream>>>(wqkv, wproj, w1, w2,
                                                wqkvT, wprojT, w1T, w2T, qscale);

    ln_kernel<<<dim3(8192), blk256, 0, stream>>>(x, ln1g, ln1b, xn);
    gemm3b<0, 1024, 3072><<<dim3(24, 32), blk512, 0, stream>>>(xn, wqkvT, qkvb, nullptr, nullptr, vT);
    attn_kernel<<<dim3(64, 16), blk256, 0, stream>>>(qkvb, vT, attnb);
    gemm3b<1, 1024, 1024><<<dim3(8, 32), blk512, 0, stream>>>(attnb, wprojT, x2, nullptr, x, nullptr);
    ln_kernel<<<dim3(8192), blk256, 0, stream>>>(x2, ln2g, ln2b, xn2);
    gemm3b<2, 1024, 4096><<<dim3(32, 32), blk512, 0, stream>>>(xn2, w1T, h1, b1, nullptr, nullptr);
    gemm3b<3, 4096, 1024><<<dim3(8, 32), blk512, 0, stream>>>(h1, w2T, out, b2, x2, nullptr);
}

// Round 5
// 496.835 us; speedup vs baseline: 1.0827x; 1.0827x over previous
//
#include <hip/hip_runtime.h>
#include <hip/hip_bf16.h>
#include <math.h>

typedef __attribute__((ext_vector_type(8))) short bf16x8;   // 8 bf16 in 4 VGPRs
typedef __attribute__((ext_vector_type(4))) float f32x4;    // MFMA C/D frag
typedef unsigned short ushort_t;

__device__ __forceinline__ ushort_t f2bf(float f) {
    union { float f; unsigned u; } v; v.f = f;
    unsigned r = v.u + 0x7FFF + ((v.u >> 16) & 1);   // RNE
    return (ushort_t)(r >> 16);
}

// pack two f32 -> 2 bf16 (round-half-up): 2 adds + 1 v_perm; a in low half
__device__ __forceinline__ unsigned pack2bf(float a, float b) {
    union { float f; unsigned u; } x, y; x.f = a; y.f = b;
    return __builtin_amdgcn_perm(y.u + 0x8000u, x.u + 0x8000u, 0x07060302u);
}

// single-instruction pair pack (RNE), a in low half
__device__ __forceinline__ unsigned cvtpk2bf(float a, float b) {
    unsigned r;
    asm("v_cvt_pk_bf16_f32 %0, %1, %2" : "=v"(r) : "v"(a), "v"(b));
    return r;
}

// async 16B global -> LDS (wave-uniform LDS base; lane data lands at base+lane*16)
__device__ __forceinline__ void gl2lds(const void* g, void* l) {
    __builtin_amdgcn_global_load_lds(
        (const __attribute__((address_space(1))) void*)g,
        (__attribute__((address_space(3))) void*)l, 16, 0, 0);
}

// fast GELU (tanh form via sigmoid): max |err| vs erf-GELU ~1e-3
__device__ __forceinline__ float fast_gelu(float tt) {
    float t2 = tt * tt;
    float arg = tt * fmaf(0.07135481283f, t2, 1.595769122f);
    float e = __builtin_amdgcn_exp2f(arg * -1.442695041f);
    return tt * __builtin_amdgcn_rcpf(1.0f + e);
}

// ---------------------------------------------------------------------------
// Merged transpose+cast for all 4 weights (one launch).
// ---------------------------------------------------------------------------
__global__ __launch_bounds__(256)
void tcast_all(const float* __restrict__ wqkv, const float* __restrict__ wproj,
               const float* __restrict__ w1, const float* __restrict__ w2,
               ushort_t* __restrict__ wqkvT, ushort_t* __restrict__ wprojT,
               ushort_t* __restrict__ w1T, ushort_t* __restrict__ w2T,
               float qscale) {
    __shared__ float tile[32][33];
    int id = blockIdx.x;
    const float* in; ushort_t* out; int R, Cc, gx, scale_n;
    if (id < 3072)      { in = wqkv;  out = wqkvT;  R = 1024; Cc = 3072; gx = 96;  scale_n = 1024; }
    else if (id < 4096) { id -= 3072; in = wproj; out = wprojT; R = 1024; Cc = 1024; gx = 32; scale_n = 0; }
    else if (id < 8192) { id -= 4096; in = w1;    out = w1T;    R = 1024; Cc = 4096; gx = 128; scale_n = 0; }
    else                { id -= 8192; in = w2;    out = w2T;    R = 4096; Cc = 1024; gx = 32; scale_n = 0; }
    int bc = (id % gx) * 32, br = (id / gx) * 32;
    int tx = threadIdx.x, ty = threadIdx.y;
    #pragma unroll
    for (int i = 0; i < 32; i += 8)
        tile[ty + i][tx] = in[(size_t)(br + ty + i) * Cc + bc + tx];
    __syncthreads();
    #pragma unroll
    for (int i = 0; i < 32; i += 8) {
        int n = bc + ty + i;
        float v = tile[tx][ty + i];
        if (n < scale_n) v *= qscale;
        out[(size_t)n * R + br + tx] = f2bf(v);
    }
}

// ---------------------------------------------------------------------------
// LayerNorm over rows of 1024, fp32 in -> bf16 out. One block (256) per row.
// ---------------------------------------------------------------------------
__global__ __launch_bounds__(256)
void ln_kernel(const float* __restrict__ x, const float* __restrict__ g,
               const float* __restrict__ b, ushort_t* __restrict__ out) {
    const int row = blockIdx.x;
    const int t = threadIdx.x;
    const float4 xv = ((const float4*)(x + (size_t)row * 1024))[t];
    float s  = xv.x + xv.y + xv.z + xv.w;
    float ss = xv.x*xv.x + xv.y*xv.y + xv.z*xv.z + xv.w*xv.w;
    #pragma unroll
    for (int off = 32; off > 0; off >>= 1) {
        s  += __shfl_xor(s, off);
        ss += __shfl_xor(ss, off);
    }
    __shared__ float red[8];
    int wave = t >> 6, lane = t & 63;
    if (lane == 0) { red[wave] = s; red[4 + wave] = ss; }
    __syncthreads();
    s  = red[0] + red[1] + red[2] + red[3];
    ss = red[4] + red[5] + red[6] + red[7];
    float mu  = s * (1.0f / 1024.0f);
    float var = ss * (1.0f / 1024.0f) - mu * mu;
    float rstd = rsqrtf(var + 1e-5f);
    float4 gv = ((const float4*)g)[t];
    float4 bv = ((const float4*)b)[t];
    ushort4 o;
    o.x = f2bf((xv.x - mu) * rstd * gv.x + bv.x);
    o.y = f2bf((xv.y - mu) * rstd * gv.y + bv.y);
    o.z = f2bf((xv.z - mu) * rstd * gv.z + bv.z);
    o.w = f2bf((xv.w - mu) * rstd * gv.w + bv.w);
    ((ushort4*)(out + (size_t)row * 1024))[t] = o;
}

// ---------------------------------------------------------------------------
// GEMM 128x256 (BMxBN), BK=64, 8 waves (2M x 4N, wave tile 64x64), 512 thr.
// 2-buffer LDS (96 KB), 4 phases per 2-K-tile iteration, 16 MFMA/phase:
//   phase = {ds_read frags (4 or 12 b128) | issue 3 gl2lds prefetch}
//           -> s_barrier -> lgkmcnt(0)+sched_barrier -> setprio(1) 16 MFMA
//           setprio(0) [-> counted vmcnt at K-tile boundary] -> s_barrier
// Staging lifecycle (steady state, tiles e=2i->buf0, o=2i+1->buf1):
//   P1: reads buf0 (B all + A frags 0,1); stages o's  B3,A0,A1 -> buf1
//   P2: reads buf0 A frags 2,3;           stages e+2' B0,B1,B2 -> buf0
//       vmcnt(3) (lands tile o = P4(i-1)+P1(i); leaves P2's 3)
//   P3: reads buf1 (B all + A frags 0,1); stages e+2' B3,A0,A1 -> buf0
//   P4: reads buf1 A frags 2,3;           stages o+2' B0,B1,B2 -> buf1
//       vmcnt(3) (lands tile e+2 = P2+P3; leaves P4's 3)
// Every region overwritten exactly >=1 phase after its last read (barrier-
// separated); vmcnt never 0 in the main loop (T4). Grids: all 4 GEMMs give
// exact multiples of 256 blocks (3/1/4/1 rounds) and %8==0 for XCD swizzle.
// MODE 0: bf16 (n0>=2048 -> vTout) | 1: f32 acc+res | 2: bf16 gelu+bias
// | 3: f32 acc+bias+res
// ---------------------------------------------------------------------------
template<int MODE, int K, int N>
__global__ __launch_bounds__(512, 2)
void gemm8p(const ushort_t* __restrict__ A, const ushort_t* __restrict__ Bt,
            void* __restrict__ Cout, const float* __restrict__ bias,
            const float* __restrict__ res, ushort_t* __restrict__ vTout) {
    constexpr int BK = 64;
    constexpr int NT = K / BK;
    constexpr int ITERS = NT / 2;
    __shared__ __align__(16) ushort_t As[2][128 * 64];   // 32 KB
    __shared__ __align__(16) ushort_t Bs[2][256 * 64];   // 64 KB
    const int tid = threadIdx.x;
    const int wave = tid >> 6, lane = tid & 63;
    const int quad = lane >> 4, l16 = lane & 15;
    const int nwg = gridDim.x * gridDim.y;
    int id = blockIdx.y * gridDim.x + blockIdx.x;
    id = (id & 7) * (nwg >> 3) + (id >> 3);
    const int gx = N / 256;
    const int m0 = (id / gx) * 128, n0 = (id % gx) * 256;
    const int wm = (wave >> 2) * 64, wn = (wave & 3) * 64;
    const int r0 = tid >> 3, pc = tid & 7;     // 64 rows x 8 chunks per call
    const int lc = pc ^ (r0 & 7);
    const ushort_t* aSrc = A  + (size_t)(m0 + r0) * K + lc * 8;
    const ushort_t* bSrc = Bt + (size_t)(n0 + r0) * K + lc * 8;
    const int swz = l16 & 7;

    f32x4 acc[4][4] = {};
    bf16x8 bfr[4][2], af[2][2];

    // staging: A tile = 2 calls (64 rows each), B tile = 4 calls
    #define STA(t, b, c) gl2lds(aSrc + (size_t)(t) * BK + (size_t)(c) * 64 * K, \
                                (char*)&As[b][0] + (c) * 8192 + wave * 1024)
    #define STB(t, b, c) gl2lds(bSrc + (size_t)(t) * BK + (size_t)(c) * 64 * K, \
                                (char*)&Bs[b][0] + (c) * 8192 + wave * 1024)
    #define LDB(buf) { _Pragma("unroll") for (int j = 0; j < 4; ++j) \
        _Pragma("unroll") for (int ks = 0; ks < 2; ++ks) \
            bfr[j][ks] = *(const bf16x8*)(&Bs[buf][(wn + j * 16 + l16) * 64 + ((ks * 4 + quad) ^ swz) * 8]); }
    #define LDA2(buf, fb) { _Pragma("unroll") for (int f = 0; f < 2; ++f) \
        _Pragma("unroll") for (int ks = 0; ks < 2; ++ks) \
            af[f][ks] = *(const bf16x8*)(&As[buf][(wm + ((fb) + f) * 16 + l16) * 64 + ((ks * 4 + quad) ^ swz) * 8]); }
    #define OPENBAR { __builtin_amdgcn_s_barrier(); \
        asm volatile("s_waitcnt lgkmcnt(0)" ::: "memory"); \
        __builtin_amdgcn_sched_barrier(0); }
    #define MM(fb) { __builtin_amdgcn_s_setprio(1); \
        _Pragma("unroll") for (int ks = 0; ks < 2; ++ks) \
        _Pragma("unroll") for (int f = 0; f < 2; ++f) \
        _Pragma("unroll") for (int j = 0; j < 4; ++j) \
            acc[(fb) + f][j] = __builtin_amdgcn_mfma_f32_16x16x32_bf16( \
                af[f][ks], bfr[j][ks], acc[(fb) + f][j], 0, 0, 0); \
        __builtin_amdgcn_s_setprio(0); }

    // prologue: tile0 -> buf0 (6 loads, issued first), tile1 B0,B1,B2 -> buf1
    STA(0, 0, 0); STA(0, 0, 1);
    STB(0, 0, 0); STB(0, 0, 1); STB(0, 0, 2); STB(0, 0, 3);
    STB(1, 1, 0); STB(1, 1, 1); STB(1, 1, 2);
    asm volatile("s_waitcnt vmcnt(3)" ::: "memory");   // tile0 landed
    __builtin_amdgcn_s_barrier();

    for (int i = 0; i < ITERS; ++i) {
        const int e = 2 * i, o = 2 * i + 1;
        const bool pre = (i + 1 < ITERS);
        // ---- P1: tile e (buf0), M-frags 0,1 + all B
        LDB(0); LDA2(0, 0);
        STB(o, 1, 3); STA(o, 1, 0); STA(o, 1, 1);      // tail of tile o
        OPENBAR; MM(0);
        __builtin_amdgcn_s_barrier();
        // ---- P2: tile e, M-frags 2,3
        LDA2(0, 2);
        if (pre) { STB(e + 2, 0, 0); STB(e + 2, 0, 1); STB(e + 2, 0, 2); }
        OPENBAR; MM(2);
        if (pre) asm volatile("s_waitcnt vmcnt(3)" ::: "memory");  // tile o landed
        else     asm volatile("s_waitcnt vmcnt(0)" ::: "memory");
        __builtin_amdgcn_s_barrier();
        // ---- P3: tile o (buf1), M-frags 0,1 + all B
        LDB(1); LDA2(1, 0);
        if (pre) { STB(e + 2, 0, 3); STA(e + 2, 0, 0); STA(e + 2, 0, 1); }
        OPENBAR; MM(0);
        __builtin_amdgcn_s_barrier();
        // ---- P4: tile o, M-frags 2,3
        LDA2(1, 2);
        if (pre) { STB(o + 2, 1, 0); STB(o + 2, 1, 1); STB(o + 2, 1, 2); }
        OPENBAR; MM(2);
        if (pre) {
            asm volatile("s_waitcnt vmcnt(3)" ::: "memory");       // tile e+2 landed
            __builtin_amdgcn_s_barrier();
        }
    }
    #undef STA
    #undef STB
    #undef LDB
    #undef LDA2
    #undef OPENBAR
    #undef MM

    // epilogue: C/D layout col = lane&15, row = quad*4 + reg
    if constexpr (MODE == 0) {
        if (vTout && n0 >= 2048) {
            #pragma unroll
            for (int i = 0; i < 4; ++i) {
                int m = m0 + wm + i * 16 + quad * 4;
                int bb = m >> 11, tq = m & 2047;
                #pragma unroll
                for (int j = 0; j < 4; ++j) {
                    int nn = n0 - 2048 + wn + j * 16 + l16;
                    int h = nn >> 6, d = nn & 63;
                    uint2 pk;
                    pk.x = pack2bf(acc[i][j][0], acc[i][j][1]);
                    pk.y = pack2bf(acc[i][j][2], acc[i][j][3]);
                    *(uint2*)(vTout + ((size_t)(bb * 16 + h) * 64 + d) * 2048 + tq) = pk;
                }
            }
            return;
        }
    }
    float bj[4];
    if constexpr (MODE == 2 || MODE == 3) {
        #pragma unroll
        for (int j = 0; j < 4; ++j) bj[j] = bias[n0 + wn + j * 16 + l16];
    }
    #pragma unroll
    for (int i = 0; i < 4; ++i) {
        #pragma unroll
        for (int j = 0; j < 4; ++j) {
            #pragma unroll
            for (int r = 0; r < 4; ++r) {
                int m = m0 + wm + i * 16 + quad * 4 + r;
                int n = n0 + wn + j * 16 + l16;
                size_t idx = (size_t)m * N + n;
                float v = acc[i][j][r];
                if constexpr (MODE == 0) {
                    ((ushort_t*)Cout)[idx] = f2bf(v);
                } else if constexpr (MODE == 1) {
                    ((float*)Cout)[idx] = v + res[idx];
                } else if constexpr (MODE == 2) {
                    ((ushort_t*)Cout)[idx] = f2bf(fast_gelu(v + bj[j]));
                } else {
                    ((float*)Cout)[idx] = v + bj[j] + res[idx];
                }
            }
        }
    }
}

// ---------------------------------------------------------------------------
// Flash attention, S^T formulation, no max-subtraction, double-buffered K/V,
// in-register P transpose via v_permlane{32,16}_swap_b32 (no P LDS round-trip).
// qkv bf16 [4,2048,3072] (Q pre-scaled by 0.125*log2e), vT [64bh][64d][2048t].
// Round-1 form (best measured 112 us): merged i-loop, cvt_pk pack, ones-MFMA
// row-sum for the softmax denominator, no setprio.
// ---------------------------------------------------------------------------
__global__ __launch_bounds__(256)
void attn_kernel(const ushort_t* __restrict__ qkv, const ushort_t* __restrict__ vT,
                 ushort_t* __restrict__ out) {
    constexpr int T = 2048, C3 = 3072, BQ = 128;
    __shared__ __align__(16) ushort_t Ks[2][64 * 64];   // [key][d], swizzled
    __shared__ __align__(16) ushort_t Vs[2][64 * 64];   // [d][key], swizzled
    const int bh = blockIdx.x, b = bh >> 4, h = bh & 15;
    const int qt = blockIdx.y;
    const int tid = threadIdx.x, wave = tid >> 6, lane = tid & 63;
    const int quad = lane >> 4, l16 = lane & 15;
    const int swz = l16 & 7;

    // Q B-frags in registers: lane l16 = q, i = q-block, ks = d-half
    bf16x8 qf[2][2];
    {
        const ushort_t* Qg = qkv + ((size_t)b * T + qt * BQ + wave * 32) * C3 + h * 64;
        #pragma unroll
        for (int i = 0; i < 2; ++i)
            #pragma unroll
            for (int ks = 0; ks < 2; ++ks)
                qf[i][ks] = *(const bf16x8*)(Qg + (size_t)(i * 16 + l16) * C3 + ks * 32 + quad * 8);
    }
    // all-ones frag: mfma(pf, ones) row-sums P on the matrix pipe
    bf16x8 onesf;
    #pragma unroll
    for (int e = 0; e < 8; ++e) onesf[e] = (short)0x3F80;   // bf16 1.0

    // staging sources (swizzled chunks)
    const int r0 = tid >> 3, pc = tid & 7;
    const int lc = pc ^ (r0 & 7);
    const ushort_t* KgB = qkv + (size_t)b * T * C3 + 1024 + h * 64 + (size_t)r0 * C3 + lc * 8;
    const ushort_t* VgB = vT + (size_t)bh * 64 * T + (size_t)r0 * T + lc * 8;
    char* kDst0 = (char*)&Ks[0][0] + wave * 1024;
    char* vDst0 = (char*)&Vs[0][0] + wave * 1024;

    f32x4 o_acc[2][4] = {};
    f32x4 l_acc[2] = {};   // row = quad*4+r (any col); accumulated via ones-MFMA

    // prologue: stage tile 0 into buffer 0
    #pragma unroll
    for (int c = 0; c < 2; ++c) {
        gl2lds(KgB + (size_t)c * 32 * C3, kDst0 + c * 4096);
        gl2lds(VgB + (size_t)c * 32 * T,  vDst0 + c * 4096);
    }

    for (int kt = 0; kt < T / 64; ++kt) {
        const int cur = kt & 1;
        __syncthreads();   // buf[cur] staged; buf[cur^1] readers (prev iter) done
        if (kt + 1 < T / 64) {
            const int nb = (cur ^ 1) * 8192;
            #pragma unroll
            for (int c = 0; c < 2; ++c) {
                gl2lds(KgB + ((size_t)(kt + 1) * 64 + c * 32) * C3, kDst0 + nb + c * 4096);
                gl2lds(VgB + (size_t)c * 32 * T + (kt + 1) * 64,    vDst0 + nb + c * 4096);
            }
        }
        const ushort_t* Kc = &Ks[cur][0];
        const ushort_t* Vc = &Vs[cur][0];

        // S^T = K * Q^T : D col = q = l16, row = key = j*16 + quad*4 + r
        f32x4 s[2][4] = {};
        #pragma unroll
        for (int ks = 0; ks < 2; ++ks) {
            const int cko = ((ks * 4 + quad) ^ swz) * 8;
            bf16x8 kf[4];
            #pragma unroll
            for (int j = 0; j < 4; ++j)
                kf[j] = *(const bf16x8*)(&Kc[(j * 16 + l16) * 64 + cko]);
            #pragma unroll
            for (int i = 0; i < 2; ++i)
                #pragma unroll
                for (int j = 0; j < 4; ++j)
                    s[i][j] = __builtin_amdgcn_mfma_f32_16x16x32_bf16(
                        kf[j], qf[i][ks], s[i][j], 0, 0, 0);
        }

        // p = 2^s, pack (v_cvt_pk_bf16_f32), transpose C-frag -> A-frag in regs.
        bf16x8 pf[2][2];
        #pragma unroll
        for (int i = 0; i < 2; ++i) {
            unsigned u[4][2];
            #pragma unroll
            for (int j = 0; j < 4; ++j) {
                float p0 = __builtin_amdgcn_exp2f(s[i][j][0]);
                float p1 = __builtin_amdgcn_exp2f(s[i][j][1]);
                float p2 = __builtin_amdgcn_exp2f(s[i][j][2]);
                float p3 = __builtin_amdgcn_exp2f(s[i][j][3]);
                u[j][0] = cvtpk2bf(p0, p1);
                u[j][1] = cvtpk2bf(p2, p3);
            }
            #pragma unroll
            for (int ks2 = 0; ks2 < 2; ++ks2) {
                unsigned d0 = u[2 * ks2][0], d2 = u[2 * ks2 + 1][0];
                asm("v_permlane32_swap_b32 %0, %1\n\t"
                    "v_permlane16_swap_b32 %0, %1" : "+v"(d0), "+v"(d2));
                unsigned d1 = u[2 * ks2][1], d3 = u[2 * ks2 + 1][1];
                asm("v_permlane32_swap_b32 %0, %1\n\t"
                    "v_permlane16_swap_b32 %0, %1" : "+v"(d1), "+v"(d3));
                union { unsigned d[4]; bf16x8 v; } fr;
                fr.d[0] = d0; fr.d[1] = d1; fr.d[2] = d2; fr.d[3] = d3;
                pf[i][ks2] = fr.v;
            }
        }

        // O += P V : A = pf (registers), B = Vs[d][key]; l += P * ones
        #pragma unroll
        for (int ks2 = 0; ks2 < 2; ++ks2) {
            const int cko = ((ks2 * 4 + quad) ^ swz) * 8;
            bf16x8 vf[4];
            #pragma unroll
            for (int j = 0; j < 4; ++j)
                vf[j] = *(const bf16x8*)(&Vc[(j * 16 + l16) * 64 + cko]);
            #pragma unroll
            for (int i = 0; i < 2; ++i) {
                #pragma unroll
                for (int j = 0; j < 4; ++j)
                    o_acc[i][j] = __builtin_amdgcn_mfma_f32_16x16x32_bf16(
                        pf[i][ks2], vf[j], o_acc[i][j], 0, 0, 0);
                l_acc[i] = __builtin_amdgcn_mfma_f32_16x16x32_bf16(
                    pf[i][ks2], onesf, l_acc[i], 0, 0, 0);
            }
        }
    }

    // normalize + store: l_acc[i][r] is the row sum for row quad*4+r (+16i)
    #pragma unroll
    for (int i = 0; i < 2; ++i) {
        #pragma unroll
        for (int r = 0; r < 4; ++r) {
            float inv = 1.0f / l_acc[i][r];
            int row = qt * BQ + wave * 32 + i * 16 + quad * 4 + r;
            size_t orow = ((size_t)b * T + row) * 1024 + h * 64;
            #pragma unroll
            for (int j = 0; j < 4; ++j)
                out[orow + j * 16 + l16] = f2bf(o_acc[i][j][r] * inv);
        }
    }
}

// ---------------------------------------------------------------------------
extern "C" void kernel_launch(void* const* d_in, const int* in_sizes, int n_in,
                              void* d_out, int out_size, void* d_ws, size_t ws_size,
                              hipStream_t stream) {
    const float* x     = (const float*)d_in[0];
    const float* ln1g  = (const float*)d_in[1];
    const float* ln1b  = (const float*)d_in[2];
    const float* ln2g  = (const float*)d_in[3];
    const float* ln2b  = (const float*)d_in[4];
    const float* wqkv  = (const float*)d_in[5];
    const float* wproj = (const float*)d_in[6];
    const float* w1    = (const float*)d_in[7];
    const float* b1    = (const float*)d_in[8];
    const float* w2    = (const float*)d_in[9];
    const float* b2    = (const float*)d_in[10];
    float* out = (float*)d_out;

    const size_t MT = 8192;  // B*T
    ushort_t* wqkvT  = (ushort_t*)d_ws;              // [3072][1024]
    ushort_t* wprojT = wqkvT  + (size_t)3072 * 1024; // [1024][1024]
    ushort_t* w1T    = wprojT + (size_t)1024 * 1024; // [4096][1024]
    ushort_t* w2T    = w1T    + (size_t)4096 * 1024; // [1024][4096]
    ushort_t* xn     = w2T    + (size_t)1024 * 4096; // [8192][1024] bf16
    ushort_t* qkvb   = xn     + MT * 1024;           // [8192][3072] bf16 (V part unused)
    ushort_t* attnb  = qkvb   + MT * 3072;           // [8192][1024] bf16
    float*    x2     = (float*)(attnb + MT * 1024);  // [8192][1024] f32
    ushort_t* xn2    = (ushort_t*)(x2 + MT * 1024);  // [8192][1024] bf16
    ushort_t* h1     = xn;                 // reuse xn+qkvb (both dead): [8192][4096]
    ushort_t* vT     = (ushort_t*)x2;      // reuse x2 region pre-proj: [64][64][2048]

    dim3 blk256(256);
    dim3 blk512(512);
    dim3 tblk(32, 8);
    const float qscale = 0.125f * 1.4426950408889634f;  // score scale * log2(e), folded into Q

    tcast_all<<<dim3(12288), tblk, 0, stream>>>(wqkv, wproj, w1, w2,
                                                wqkvT, wprojT, w1T, w2T, qscale);

    ln_kernel<<<dim3(8192), blk256, 0, stream>>>(x, ln1g, ln1b, xn);
    gemm8p<0, 1024, 3072><<<dim3(12, 64), blk512, 0, stream>>>(xn, wqkvT, qkvb, nullptr, nullptr, vT);
    attn_kernel<<<dim3(64, 16), blk256, 0, stream>>>(qkvb, vT, attnb);
    gemm8p<1, 1024, 1024><<<dim3(4, 64), blk512, 0, stream>>>(attnb, wprojT, x2, nullptr, x, nullptr);
    ln_kernel<<<dim3(8192), blk256, 0, stream>>>(x2, ln2g, ln2b, xn2);
    gemm8p<2, 1024, 4096><<<dim3(16, 64), blk512, 0, stream>>>(xn2, w1T, h1, b1, nullptr, nullptr);
    gemm8p<3, 4096, 1024><<<dim3(4, 64), blk512, 0, stream>>>(h1, w2T, out, b2, x2, nullptr);
}

// Round 6
// 495.094 us; speedup vs baseline: 1.0865x; 1.0035x over previous
//
#include <hip/hip_runtime.h>
#include <hip/hip_bf16.h>
#include <math.h>

typedef __attribute__((ext_vector_type(8))) short bf16x8;   // 8 bf16 in 4 VGPRs
typedef __attribute__((ext_vector_type(4))) float f32x4;    // MFMA C/D frag
typedef unsigned short ushort_t;

__device__ __forceinline__ ushort_t f2bf(float f) {
    union { float f; unsigned u; } v; v.f = f;
    unsigned r = v.u + 0x7FFF + ((v.u >> 16) & 1);   // RNE
    return (ushort_t)(r >> 16);
}

// pack two f32 -> 2 bf16 (round-half-up): 2 adds + 1 v_perm; a in low half
__device__ __forceinline__ unsigned pack2bf(float a, float b) {
    union { float f; unsigned u; } x, y; x.f = a; y.f = b;
    return __builtin_amdgcn_perm(y.u + 0x8000u, x.u + 0x8000u, 0x07060302u);
}

// single-instruction pair pack (RNE), a in low half
__device__ __forceinline__ unsigned cvtpk2bf(float a, float b) {
    unsigned r;
    asm("v_cvt_pk_bf16_f32 %0, %1, %2" : "=v"(r) : "v"(a), "v"(b));
    return r;
}

// async 16B global -> LDS (wave-uniform LDS base; lane data lands at base+lane*16)
__device__ __forceinline__ void gl2lds(const void* g, void* l) {
    __builtin_amdgcn_global_load_lds(
        (const __attribute__((address_space(1))) void*)g,
        (__attribute__((address_space(3))) void*)l, 16, 0, 0);
}

// fast GELU (tanh form via sigmoid): max |err| vs erf-GELU ~1e-3
__device__ __forceinline__ float fast_gelu(float tt) {
    float t2 = tt * tt;
    float arg = tt * fmaf(0.07135481283f, t2, 1.595769122f);
    float e = __builtin_amdgcn_exp2f(arg * -1.442695041f);
    return tt * __builtin_amdgcn_rcpf(1.0f + e);
}

// ---------------------------------------------------------------------------
// Merged transpose+cast for all 4 weights (one launch).
// ---------------------------------------------------------------------------
__global__ __launch_bounds__(256)
void tcast_all(const float* __restrict__ wqkv, const float* __restrict__ wproj,
               const float* __restrict__ w1, const float* __restrict__ w2,
               ushort_t* __restrict__ wqkvT, ushort_t* __restrict__ wprojT,
               ushort_t* __restrict__ w1T, ushort_t* __restrict__ w2T,
               float qscale) {
    __shared__ float tile[32][33];
    int id = blockIdx.x;
    const float* in; ushort_t* out; int R, Cc, gx, scale_n;
    if (id < 3072)      { in = wqkv;  out = wqkvT;  R = 1024; Cc = 3072; gx = 96;  scale_n = 1024; }
    else if (id < 4096) { id -= 3072; in = wproj; out = wprojT; R = 1024; Cc = 1024; gx = 32; scale_n = 0; }
    else if (id < 8192) { id -= 4096; in = w1;    out = w1T;    R = 1024; Cc = 4096; gx = 128; scale_n = 0; }
    else                { id -= 8192; in = w2;    out = w2T;    R = 4096; Cc = 1024; gx = 32; scale_n = 0; }
    int bc = (id % gx) * 32, br = (id / gx) * 32;
    int tx = threadIdx.x, ty = threadIdx.y;
    #pragma unroll
    for (int i = 0; i < 32; i += 8)
        tile[ty + i][tx] = in[(size_t)(br + ty + i) * Cc + bc + tx];
    __syncthreads();
    #pragma unroll
    for (int i = 0; i < 32; i += 8) {
        int n = bc + ty + i;
        float v = tile[tx][ty + i];
        if (n < scale_n) v *= qscale;
        out[(size_t)n * R + br + tx] = f2bf(v);
    }
}

// ---------------------------------------------------------------------------
// LayerNorm over rows of 1024, fp32 in -> bf16 out. One block (256) per row.
// ---------------------------------------------------------------------------
__global__ __launch_bounds__(256)
void ln_kernel(const float* __restrict__ x, const float* __restrict__ g,
               const float* __restrict__ b, ushort_t* __restrict__ out) {
    const int row = blockIdx.x;
    const int t = threadIdx.x;
    const float4 xv = ((const float4*)(x + (size_t)row * 1024))[t];
    float s  = xv.x + xv.y + xv.z + xv.w;
    float ss = xv.x*xv.x + xv.y*xv.y + xv.z*xv.z + xv.w*xv.w;
    #pragma unroll
    for (int off = 32; off > 0; off >>= 1) {
        s  += __shfl_xor(s, off);
        ss += __shfl_xor(ss, off);
    }
    __shared__ float red[8];
    int wave = t >> 6, lane = t & 63;
    if (lane == 0) { red[wave] = s; red[4 + wave] = ss; }
    __syncthreads();
    s  = red[0] + red[1] + red[2] + red[3];
    ss = red[4] + red[5] + red[6] + red[7];
    float mu  = s * (1.0f / 1024.0f);
    float var = ss * (1.0f / 1024.0f) - mu * mu;
    float rstd = rsqrtf(var + 1e-5f);
    float4 gv = ((const float4*)g)[t];
    float4 bv = ((const float4*)b)[t];
    ushort4 o;
    o.x = f2bf((xv.x - mu) * rstd * gv.x + bv.x);
    o.y = f2bf((xv.y - mu) * rstd * gv.y + bv.y);
    o.z = f2bf((xv.z - mu) * rstd * gv.z + bv.z);
    o.w = f2bf((xv.w - mu) * rstd * gv.w + bv.w);
    ((ushort4*)(out + (size_t)row * 1024))[t] = o;
}

// ---------------------------------------------------------------------------
// GEMM 128x128 (legacy, proven): used for N=1024 outputs (proj, ff2).
// MODE 1: f32 = acc+res | 3: f32 = acc+bias+res
// ---------------------------------------------------------------------------
template<int MODE, int K, int N>
__global__ __launch_bounds__(256)
void gemm_bt(const ushort_t* __restrict__ A, const ushort_t* __restrict__ Bt,
             void* __restrict__ Cout, const float* __restrict__ bias,
             const float* __restrict__ res, ushort_t* __restrict__ vTout) {
    constexpr int BK = 64;
    __shared__ __align__(16) ushort_t As[128 * 64];
    __shared__ __align__(16) ushort_t Bs[128 * 64];
    const int tid = threadIdx.x;
    const int wave = tid >> 6, lane = tid & 63;
    const int quad = lane >> 4, l16 = lane & 15;
    const int m0 = blockIdx.y * 128, n0 = blockIdx.x * 128;
    const int wm = (wave >> 1) * 64, wn = (wave & 1) * 64;

    const int r0 = tid >> 3, pc = tid & 7;
    const int lc = pc ^ (r0 & 7);
    const ushort_t* aSrc = A  + (size_t)(m0 + r0) * K + lc * 8;
    const ushort_t* bSrc = Bt + (size_t)(n0 + r0) * K + lc * 8;
    char* aDst = (char*)As + wave * 1024;
    char* bDst = (char*)Bs + wave * 1024;
    const int swz = l16 & 7;

    f32x4 acc[4][4] = {};

    for (int k0 = 0; k0 < K; k0 += BK) {
        __syncthreads();
        #pragma unroll
        for (int c = 0; c < 4; ++c) {
            gl2lds(aSrc + (size_t)c * 32 * K + k0, aDst + c * 4096);
            gl2lds(bSrc + (size_t)c * 32 * K + k0, bDst + c * 4096);
        }
        __syncthreads();
        #pragma unroll
        for (int ks = 0; ks < 2; ++ks) {
            const int cko = ((ks * 4 + quad) ^ swz) * 8;
            bf16x8 af[4], bfr[4];
            #pragma unroll
            for (int i = 0; i < 4; ++i)
                af[i] = *(const bf16x8*)(&As[(wm + i * 16 + l16) * 64 + cko]);
            #pragma unroll
            for (int j = 0; j < 4; ++j)
                bfr[j] = *(const bf16x8*)(&Bs[(wn + j * 16 + l16) * 64 + cko]);
            #pragma unroll
            for (int i = 0; i < 4; ++i)
                #pragma unroll
                for (int j = 0; j < 4; ++j)
                    acc[i][j] = __builtin_amdgcn_mfma_f32_16x16x32_bf16(
                        af[i], bfr[j], acc[i][j], 0, 0, 0);
        }
    }

    float bj[4];
    if constexpr (MODE == 2 || MODE == 3) {
        #pragma unroll
        for (int j = 0; j < 4; ++j) bj[j] = bias[n0 + wn + j * 16 + l16];
    }
    #pragma unroll
    for (int i = 0; i < 4; ++i) {
        #pragma unroll
        for (int j = 0; j < 4; ++j) {
            #pragma unroll
            for (int r = 0; r < 4; ++r) {
                int m = m0 + wm + i * 16 + quad * 4 + r;
                int n = n0 + wn + j * 16 + l16;
                size_t idx = (size_t)m * N + n;
                float v = acc[i][j][r];
                if constexpr (MODE == 0) {
                    ((ushort_t*)Cout)[idx] = f2bf(v);
                } else if constexpr (MODE == 1) {
                    ((float*)Cout)[idx] = v + res[idx];
                } else if constexpr (MODE == 2) {
                    ((ushort_t*)Cout)[idx] = f2bf(fast_gelu(v + bj[j]));
                } else {
                    ((float*)Cout)[idx] = v + bj[j] + res[idx];
                }
            }
        }
    }
}

// ---------------------------------------------------------------------------
// GEMM 256x256 (m201-faithful), BK=64, 8 waves, WAVE TILE 128x64 (2M x 4N),
// 512 thr, 2-buffer LDS 128 KB, 8 phases per 2-K-tile iteration, 16 MFMA/ph.
// Staging lifecycle (iter i: tiles e=2i->buf0, o=2i+1->buf1), 2-4 loads/ph:
//   P0: read B(e) all + A(e) f01 | stage A(o)c01   (As1 freed prev P7)
//   P1: read A(e) f23            | stage A(o)c23, B(e+2)c01 (Bs0 freed P0)
//   P2: read A(e) f45            | stage B(e+2)c23
//   P3: read A(e) f67            | vmcnt(4): B(o)+A(o) land, B(e+2) in flight
//   P4: read B(o) all + A(o) f01 | stage A(e+2)c01 (As0 freed P3)
//   P5: read A(o) f23            | stage A(e+2)c23
//   P6: read A(o) f45            | stage B(o+2)c01 (Bs1 freed P4)
//   P7: read A(o) f67            | stage B(o+2)c23; vmcnt(4): B/A(e+2) land,
//       B(o+2) in flight = loop invariant (start-of-iter outstanding = 4).
// vmcnt never 0 in steady state (T4); phase = ds_read|stage -> barrier ->
// lgkmcnt(0)+sched_barrier -> setprio(1) 16 MFMA setprio(0) -> barrier.
// MODE 0: bf16 (n0>=2048 -> vTout) | 2: bf16 gelu(acc+bias)
// ---------------------------------------------------------------------------
template<int MODE, int K, int N>
__global__ __launch_bounds__(512, 2)
void gemm256p(const ushort_t* __restrict__ A, const ushort_t* __restrict__ Bt,
              void* __restrict__ Cout, const float* __restrict__ bias,
              const float* __restrict__ res, ushort_t* __restrict__ vTout) {
    constexpr int BK = 64;
    constexpr int NT = K / BK;
    constexpr int ITERS = NT / 2;
    __shared__ __align__(16) ushort_t As[2][256 * 64];   // 64 KB
    __shared__ __align__(16) ushort_t Bs[2][256 * 64];   // 64 KB
    const int tid = threadIdx.x;
    const int wave = tid >> 6, lane = tid & 63;
    const int quad = lane >> 4, l16 = lane & 15;
    const int nwg = gridDim.x * gridDim.y;
    int id = blockIdx.y * gridDim.x + blockIdx.x;
    id = (id & 7) * (nwg >> 3) + (id >> 3);              // bijective, nwg%8==0
    const int m0 = (id / gridDim.x) * 256, n0 = (id % gridDim.x) * 256;
    const int wm = (wave >> 2) * 128, wn = (wave & 3) * 64;
    const int r0 = tid >> 3, pc = tid & 7;               // 64 rows x 8 chunks/call
    const int lc = pc ^ (r0 & 7);
    const ushort_t* aSrc = A  + (size_t)(m0 + r0) * K + lc * 8;
    const ushort_t* bSrc = Bt + (size_t)(n0 + r0) * K + lc * 8;
    const int swz = l16 & 7;

    f32x4 acc[8][4] = {};
    bf16x8 bfr[4][2], af[2][2];

    #define STA(t, b, c) gl2lds(aSrc + (size_t)(t) * BK + (size_t)(c) * 64 * K, \
                                (char*)&As[b][0] + (c) * 8192 + wave * 1024)
    #define STB(t, b, c) gl2lds(bSrc + (size_t)(t) * BK + (size_t)(c) * 64 * K, \
                                (char*)&Bs[b][0] + (c) * 8192 + wave * 1024)
    #define LDB(buf) { _Pragma("unroll") for (int j = 0; j < 4; ++j) \
        _Pragma("unroll") for (int ks = 0; ks < 2; ++ks) \
            bfr[j][ks] = *(const bf16x8*)(&Bs[buf][(wn + j * 16 + l16) * 64 + ((ks * 4 + quad) ^ swz) * 8]); }
    #define LDA2(buf, fb) { _Pragma("unroll") for (int f = 0; f < 2; ++f) \
        _Pragma("unroll") for (int ks = 0; ks < 2; ++ks) \
            af[f][ks] = *(const bf16x8*)(&As[buf][(wm + ((fb) + f) * 16 + l16) * 64 + ((ks * 4 + quad) ^ swz) * 8]); }
    #define BARW { __builtin_amdgcn_s_barrier(); \
        asm volatile("s_waitcnt lgkmcnt(0)" ::: "memory"); \
        __builtin_amdgcn_sched_barrier(0); }
    #define MM(fb) { __builtin_amdgcn_s_setprio(1); \
        _Pragma("unroll") for (int ks = 0; ks < 2; ++ks) \
        _Pragma("unroll") for (int f = 0; f < 2; ++f) \
        _Pragma("unroll") for (int j = 0; j < 4; ++j) \
            acc[(fb) + f][j] = __builtin_amdgcn_mfma_f32_16x16x32_bf16( \
                af[f][ks], bfr[j][ks], acc[(fb) + f][j], 0, 0, 0); \
        __builtin_amdgcn_s_setprio(0); }
    #define CBAR __builtin_amdgcn_s_barrier();

    // prologue: B0->Bs0, A0->As0, B1->Bs1 (12 loads); B0+A0 landed, B1 in flight
    STB(0, 0, 0); STB(0, 0, 1); STB(0, 0, 2); STB(0, 0, 3);
    STA(0, 0, 0); STA(0, 0, 1); STA(0, 0, 2); STA(0, 0, 3);
    STB(1, 1, 0); STB(1, 1, 1); STB(1, 1, 2); STB(1, 1, 3);
    asm volatile("s_waitcnt vmcnt(4)" ::: "memory");
    __builtin_amdgcn_s_barrier();

    for (int i = 0; i < ITERS; ++i) {
        const int e = 2 * i, o = 2 * i + 1;
        const bool pre = (i + 1 < ITERS);
        // P0
        LDB(0); LDA2(0, 0);
        STA(o, 1, 0); STA(o, 1, 1);
        BARW; MM(0); CBAR;
        // P1
        LDA2(0, 2);
        STA(o, 1, 2); STA(o, 1, 3);
        if (pre) { STB(e + 2, 0, 0); STB(e + 2, 0, 1); }
        BARW; MM(2); CBAR;
        // P2
        LDA2(0, 4);
        if (pre) { STB(e + 2, 0, 2); STB(e + 2, 0, 3); }
        BARW; MM(4); CBAR;
        // P3  (wait alpha: tile o fully landed; B(e+2) stays in flight)
        LDA2(0, 6);
        BARW; MM(6);
        if (pre) asm volatile("s_waitcnt vmcnt(4)" ::: "memory");
        else     asm volatile("s_waitcnt vmcnt(0)" ::: "memory");
        CBAR;
        // P4
        LDB(1); LDA2(1, 0);
        if (pre) { STA(e + 2, 0, 0); STA(e + 2, 0, 1); }
        BARW; MM(0); CBAR;
        // P5
        LDA2(1, 2);
        if (pre) { STA(e + 2, 0, 2); STA(e + 2, 0, 3); }
        BARW; MM(2); CBAR;
        // P6
        LDA2(1, 4);
        if (pre) { STB(o + 2, 1, 0); STB(o + 2, 1, 1); }
        BARW; MM(4); CBAR;
        // P7  (wait beta: tile e+2 fully landed; B(o+2) stays in flight)
        LDA2(1, 6);
        if (pre) { STB(o + 2, 1, 2); STB(o + 2, 1, 3); }
        BARW; MM(6);
        if (pre) {
            asm volatile("s_waitcnt vmcnt(4)" ::: "memory");
            CBAR;
        }
    }
    #undef STA
    #undef STB
    #undef LDB
    #undef LDA2
    #undef BARW
    #undef MM
    #undef CBAR

    // epilogue: C/D layout col = lane&15, row = quad*4 + reg
    if constexpr (MODE == 0) {
        if (vTout && n0 >= 2048) {
            #pragma unroll
            for (int i = 0; i < 8; ++i) {
                int m = m0 + wm + i * 16 + quad * 4;
                int bb = m >> 11, tq = m & 2047;
                #pragma unroll
                for (int j = 0; j < 4; ++j) {
                    int nn = n0 - 2048 + wn + j * 16 + l16;
                    int h = nn >> 6, d = nn & 63;
                    uint2 pk;
                    pk.x = pack2bf(acc[i][j][0], acc[i][j][1]);
                    pk.y = pack2bf(acc[i][j][2], acc[i][j][3]);
                    *(uint2*)(vTout + ((size_t)(bb * 16 + h) * 64 + d) * 2048 + tq) = pk;
                }
            }
            return;
        }
    }
    float bj[4];
    if constexpr (MODE == 2) {
        #pragma unroll
        for (int j = 0; j < 4; ++j) bj[j] = bias[n0 + wn + j * 16 + l16];
    }
    #pragma unroll
    for (int i = 0; i < 8; ++i) {
        #pragma unroll
        for (int j = 0; j < 4; ++j) {
            #pragma unroll
            for (int r = 0; r < 4; ++r) {
                int m = m0 + wm + i * 16 + quad * 4 + r;
                int n = n0 + wn + j * 16 + l16;
                size_t idx = (size_t)m * N + n;
                float v = acc[i][j][r];
                if constexpr (MODE == 0) {
                    ((ushort_t*)Cout)[idx] = f2bf(v);
                } else if constexpr (MODE == 2) {
                    ((ushort_t*)Cout)[idx] = f2bf(fast_gelu(v + bj[j]));
                }
            }
        }
    }
}

// ---------------------------------------------------------------------------
// Flash attention, S^T formulation, no max-subtraction, double-buffered K/V,
// in-register P transpose via v_permlane{32,16}_swap_b32 (no P LDS round-trip).
// qkv bf16 [4,2048,3072] (Q pre-scaled by 0.125*log2e), vT [64bh][64d][2048t].
// Round-1 form (best measured 112 us).
// ---------------------------------------------------------------------------
__global__ __launch_bounds__(256)
void attn_kernel(const ushort_t* __restrict__ qkv, const ushort_t* __restrict__ vT,
                 ushort_t* __restrict__ out) {
    constexpr int T = 2048, C3 = 3072, BQ = 128;
    __shared__ __align__(16) ushort_t Ks[2][64 * 64];   // [key][d], swizzled
    __shared__ __align__(16) ushort_t Vs[2][64 * 64];   // [d][key], swizzled
    const int bh = blockIdx.x, b = bh >> 4, h = bh & 15;
    const int qt = blockIdx.y;
    const int tid = threadIdx.x, wave = tid >> 6, lane = tid & 63;
    const int quad = lane >> 4, l16 = lane & 15;
    const int swz = l16 & 7;

    bf16x8 qf[2][2];
    {
        const ushort_t* Qg = qkv + ((size_t)b * T + qt * BQ + wave * 32) * C3 + h * 64;
        #pragma unroll
        for (int i = 0; i < 2; ++i)
            #pragma unroll
            for (int ks = 0; ks < 2; ++ks)
                qf[i][ks] = *(const bf16x8*)(Qg + (size_t)(i * 16 + l16) * C3 + ks * 32 + quad * 8);
    }
    bf16x8 onesf;
    #pragma unroll
    for (int e = 0; e < 8; ++e) onesf[e] = (short)0x3F80;   // bf16 1.0

    const int r0 = tid >> 3, pc = tid & 7;
    const int lc = pc ^ (r0 & 7);
    const ushort_t* KgB = qkv + (size_t)b * T * C3 + 1024 + h * 64 + (size_t)r0 * C3 + lc * 8;
    const ushort_t* VgB = vT + (size_t)bh * 64 * T + (size_t)r0 * T + lc * 8;
    char* kDst0 = (char*)&Ks[0][0] + wave * 1024;
    char* vDst0 = (char*)&Vs[0][0] + wave * 1024;

    f32x4 o_acc[2][4] = {};
    f32x4 l_acc[2] = {};

    #pragma unroll
    for (int c = 0; c < 2; ++c) {
        gl2lds(KgB + (size_t)c * 32 * C3, kDst0 + c * 4096);
        gl2lds(VgB + (size_t)c * 32 * T,  vDst0 + c * 4096);
    }

    for (int kt = 0; kt < T / 64; ++kt) {
        const int cur = kt & 1;
        __syncthreads();
        if (kt + 1 < T / 64) {
            const int nb = (cur ^ 1) * 8192;
            #pragma unroll
            for (int c = 0; c < 2; ++c) {
                gl2lds(KgB + ((size_t)(kt + 1) * 64 + c * 32) * C3, kDst0 + nb + c * 4096);
                gl2lds(VgB + (size_t)c * 32 * T + (kt + 1) * 64,    vDst0 + nb + c * 4096);
            }
        }
        const ushort_t* Kc = &Ks[cur][0];
        const ushort_t* Vc = &Vs[cur][0];

        f32x4 s[2][4] = {};
        #pragma unroll
        for (int ks = 0; ks < 2; ++ks) {
            const int cko = ((ks * 4 + quad) ^ swz) * 8;
            bf16x8 kf[4];
            #pragma unroll
            for (int j = 0; j < 4; ++j)
                kf[j] = *(const bf16x8*)(&Kc[(j * 16 + l16) * 64 + cko]);
            #pragma unroll
            for (int i = 0; i < 2; ++i)
                #pragma unroll
                for (int j = 0; j < 4; ++j)
                    s[i][j] = __builtin_amdgcn_mfma_f32_16x16x32_bf16(
                        kf[j], qf[i][ks], s[i][j], 0, 0, 0);
        }

        bf16x8 pf[2][2];
        #pragma unroll
        for (int i = 0; i < 2; ++i) {
            unsigned u[4][2];
            #pragma unroll
            for (int j = 0; j < 4; ++j) {
                float p0 = __builtin_amdgcn_exp2f(s[i][j][0]);
                float p1 = __builtin_amdgcn_exp2f(s[i][j][1]);
                float p2 = __builtin_amdgcn_exp2f(s[i][j][2]);
                float p3 = __builtin_amdgcn_exp2f(s[i][j][3]);
                u[j][0] = cvtpk2bf(p0, p1);
                u[j][1] = cvtpk2bf(p2, p3);
            }
            #pragma unroll
            for (int ks2 = 0; ks2 < 2; ++ks2) {
                unsigned d0 = u[2 * ks2][0], d2 = u[2 * ks2 + 1][0];
                asm("v_permlane32_swap_b32 %0, %1\n\t"
                    "v_permlane16_swap_b32 %0, %1" : "+v"(d0), "+v"(d2));
                unsigned d1 = u[2 * ks2][1], d3 = u[2 * ks2 + 1][1];
                asm("v_permlane32_swap_b32 %0, %1\n\t"
                    "v_permlane16_swap_b32 %0, %1" : "+v"(d1), "+v"(d3));
                union { unsigned d[4]; bf16x8 v; } fr;
                fr.d[0] = d0; fr.d[1] = d1; fr.d[2] = d2; fr.d[3] = d3;
                pf[i][ks2] = fr.v;
            }
        }

        #pragma unroll
        for (int ks2 = 0; ks2 < 2; ++ks2) {
            const int cko = ((ks2 * 4 + quad) ^ swz) * 8;
            bf16x8 vf[4];
            #pragma unroll
            for (int j = 0; j < 4; ++j)
                vf[j] = *(const bf16x8*)(&Vc[(j * 16 + l16) * 64 + cko]);
            #pragma unroll
            for (int i = 0; i < 2; ++i) {
                #pragma unroll
                for (int j = 0; j < 4; ++j)
                    o_acc[i][j] = __builtin_amdgcn_mfma_f32_16x16x32_bf16(
                        pf[i][ks2], vf[j], o_acc[i][j], 0, 0, 0);
                l_acc[i] = __builtin_amdgcn_mfma_f32_16x16x32_bf16(
                    pf[i][ks2], onesf, l_acc[i], 0, 0, 0);
            }
        }
    }

    #pragma unroll
    for (int i = 0; i < 2; ++i) {
        #pragma unroll
        for (int r = 0; r < 4; ++r) {
            float inv = 1.0f / l_acc[i][r];
            int row = qt * BQ + wave * 32 + i * 16 + quad * 4 + r;
            size_t orow = ((size_t)b * T + row) * 1024 + h * 64;
            #pragma unroll
            for (int j = 0; j < 4; ++j)
                out[orow + j * 16 + l16] = f2bf(o_acc[i][j][r] * inv);
        }
    }
}

// ---------------------------------------------------------------------------
extern "C" void kernel_launch(void* const* d_in, const int* in_sizes, int n_in,
                              void* d_out, int out_size, void* d_ws, size_t ws_size,
                              hipStream_t stream) {
    const float* x     = (const float*)d_in[0];
    const float* ln1g  = (const float*)d_in[1];
    const float* ln1b  = (const float*)d_in[2];
    const float* ln2g  = (const float*)d_in[3];
    const float* ln2b  = (const float*)d_in[4];
    const float* wqkv  = (const float*)d_in[5];
    const float* wproj = (const float*)d_in[6];
    const float* w1    = (const float*)d_in[7];
    const float* b1    = (const float*)d_in[8];
    const float* w2    = (const float*)d_in[9];
    const float* b2    = (const float*)d_in[10];
    float* out = (float*)d_out;

    const size_t MT = 8192;  // B*T
    ushort_t* wqkvT  = (ushort_t*)d_ws;              // [3072][1024]
    ushort_t* wprojT = wqkvT  + (size_t)3072 * 1024; // [1024][1024]
    ushort_t* w1T    = wprojT + (size_t)1024 * 1024; // [4096][1024]
    ushort_t* w2T    = w1T    + (size_t)4096 * 1024; // [1024][4096]
    ushort_t* xn     = w2T    + (size_t)1024 * 4096; // [8192][1024] bf16
    ushort_t* qkvb   = xn     + MT * 1024;           // [8192][3072] bf16 (V part unused)
    ushort_t* attnb  = qkvb   + MT * 3072;           // [8192][1024] bf16
    float*    x2     = (float*)(attnb + MT * 1024);  // [8192][1024] f32
    ushort_t* xn2    = (ushort_t*)(x2 + MT * 1024);  // [8192][1024] bf16
    ushort_t* h1     = xn;                 // reuse xn+qkvb (both dead): [8192][4096]
    ushort_t* vT     = (ushort_t*)x2;      // reuse x2 region pre-proj: [64][64][2048]

    dim3 blk256(256);
    dim3 blk512(512);
    dim3 tblk(32, 8);
    const float qscale = 0.125f * 1.4426950408889634f;  // score scale * log2(e), folded into Q

    tcast_all<<<dim3(12288), tblk, 0, stream>>>(wqkv, wproj, w1, w2,
                                                wqkvT, wprojT, w1T, w2T, qscale);

    ln_kernel<<<dim3(8192), blk256, 0, stream>>>(x, ln1g, ln1b, xn);
    gemm256p<0, 1024, 3072><<<dim3(12, 32), blk512, 0, stream>>>(xn, wqkvT, qkvb, nullptr, nullptr, vT);
    attn_kernel<<<dim3(64, 16), blk256, 0, stream>>>(qkvb, vT, attnb);
    gemm_bt<1, 1024, 1024><<<dim3(8, 64), blk256, 0, stream>>>(attnb, wprojT, x2, nullptr, x, nullptr);
    ln_kernel<<<dim3(8192), blk256, 0, stream>>>(x2, ln2g, ln2b, xn2);
    gemm256p<2, 1024, 4096><<<dim3(16, 32), blk512, 0, stream>>>(xn2, w1T, h1, b1, nullptr, nullptr);
    gemm_bt<3, 4096, 1024><<<dim3(8, 64), blk256, 0, stream>>>(h1, w2T, out, b2, x2, nullptr);
}

// Round 7
// 486.076 us; speedup vs baseline: 1.1067x; 1.0186x over previous
//
#include <hip/hip_runtime.h>
#include <hip/hip_bf16.h>
#include <math.h>

typedef __attribute__((ext_vector_type(8))) short bf16x8;   // 8 bf16 in 4 VGPRs
typedef __attribute__((ext_vector_type(4))) float f32x4;    // MFMA C/D frag
typedef unsigned short ushort_t;

__device__ __forceinline__ ushort_t f2bf(float f) {
    union { float f; unsigned u; } v; v.f = f;
    unsigned r = v.u + 0x7FFF + ((v.u >> 16) & 1);   // RNE
    return (ushort_t)(r >> 16);
}

// pack two f32 -> 2 bf16 (round-half-up): 2 adds + 1 v_perm; a in low half
__device__ __forceinline__ unsigned pack2bf(float a, float b) {
    union { float f; unsigned u; } x, y; x.f = a; y.f = b;
    return __builtin_amdgcn_perm(y.u + 0x8000u, x.u + 0x8000u, 0x07060302u);
}

// single-instruction pair pack (RNE), a in low half
__device__ __forceinline__ unsigned cvtpk2bf(float a, float b) {
    unsigned r;
    asm("v_cvt_pk_bf16_f32 %0, %1, %2" : "=v"(r) : "v"(a), "v"(b));
    return r;
}

// async 16B global -> LDS (wave-uniform LDS base; lane data lands at base+lane*16)
__device__ __forceinline__ void gl2lds(const void* g, void* l) {
    __builtin_amdgcn_global_load_lds(
        (const __attribute__((address_space(1))) void*)g,
        (__attribute__((address_space(3))) void*)l, 16, 0, 0);
}

// fast GELU (tanh form via sigmoid): max |err| vs erf-GELU ~1e-3
__device__ __forceinline__ float fast_gelu(float tt) {
    float t2 = tt * tt;
    float arg = tt * fmaf(0.07135481283f, t2, 1.595769122f);
    float e = __builtin_amdgcn_exp2f(arg * -1.442695041f);
    return tt * __builtin_amdgcn_rcpf(1.0f + e);
}

// ---------------------------------------------------------------------------
// Merged transpose+cast for all 4 weights (one launch).
// ---------------------------------------------------------------------------
__global__ __launch_bounds__(256)
void tcast_all(const float* __restrict__ wqkv, const float* __restrict__ wproj,
               const float* __restrict__ w1, const float* __restrict__ w2,
               ushort_t* __restrict__ wqkvT, ushort_t* __restrict__ wprojT,
               ushort_t* __restrict__ w1T, ushort_t* __restrict__ w2T,
               float qscale) {
    __shared__ float tile[32][33];
    int id = blockIdx.x;
    const float* in; ushort_t* out; int R, Cc, gx, scale_n;
    if (id < 3072)      { in = wqkv;  out = wqkvT;  R = 1024; Cc = 3072; gx = 96;  scale_n = 1024; }
    else if (id < 4096) { id -= 3072; in = wproj; out = wprojT; R = 1024; Cc = 1024; gx = 32; scale_n = 0; }
    else if (id < 8192) { id -= 4096; in = w1;    out = w1T;    R = 1024; Cc = 4096; gx = 128; scale_n = 0; }
    else                { id -= 8192; in = w2;    out = w2T;    R = 4096; Cc = 1024; gx = 32; scale_n = 0; }
    int bc = (id % gx) * 32, br = (id / gx) * 32;
    int tx = threadIdx.x, ty = threadIdx.y;
    #pragma unroll
    for (int i = 0; i < 32; i += 8)
        tile[ty + i][tx] = in[(size_t)(br + ty + i) * Cc + bc + tx];
    __syncthreads();
    #pragma unroll
    for (int i = 0; i < 32; i += 8) {
        int n = bc + ty + i;
        float v = tile[tx][ty + i];
        if (n < scale_n) v *= qscale;
        out[(size_t)n * R + br + tx] = f2bf(v);
    }
}

// ---------------------------------------------------------------------------
// LayerNorm over rows of 1024, fp32 in -> bf16 out. One block (256) per row.
// ---------------------------------------------------------------------------
__global__ __launch_bounds__(256)
void ln_kernel(const float* __restrict__ x, const float* __restrict__ g,
               const float* __restrict__ b, ushort_t* __restrict__ out) {
    const int row = blockIdx.x;
    const int t = threadIdx.x;
    const float4 xv = ((const float4*)(x + (size_t)row * 1024))[t];
    float s  = xv.x + xv.y + xv.z + xv.w;
    float ss = xv.x*xv.x + xv.y*xv.y + xv.z*xv.z + xv.w*xv.w;
    #pragma unroll
    for (int off = 32; off > 0; off >>= 1) {
        s  += __shfl_xor(s, off);
        ss += __shfl_xor(ss, off);
    }
    __shared__ float red[8];
    int wave = t >> 6, lane = t & 63;
    if (lane == 0) { red[wave] = s; red[4 + wave] = ss; }
    __syncthreads();
    s  = red[0] + red[1] + red[2] + red[3];
    ss = red[4] + red[5] + red[6] + red[7];
    float mu  = s * (1.0f / 1024.0f);
    float var = ss * (1.0f / 1024.0f) - mu * mu;
    float rstd = rsqrtf(var + 1e-5f);
    float4 gv = ((const float4*)g)[t];
    float4 bv = ((const float4*)b)[t];
    ushort4 o;
    o.x = f2bf((xv.x - mu) * rstd * gv.x + bv.x);
    o.y = f2bf((xv.y - mu) * rstd * gv.y + bv.y);
    o.z = f2bf((xv.z - mu) * rstd * gv.z + bv.z);
    o.w = f2bf((xv.w - mu) * rstd * gv.w + bv.w);
    ((ushort4*)(out + (size_t)row * 1024))[t] = o;
}

// ---------------------------------------------------------------------------
// GEMM: C[M,N] = A[M,K] * Bt[N,K], bf16 in, fp32 acc. 128x128 tile, BK=64.
// XOR-swizzled LDS (chunk ^= row&7) applied at the GLOBAL source address.
// T1 bijective chunked XCD swizzle: XCD c owns a CONTIGUOUS chunk of the
// (m,n) grid (n varies fastest within the chunk) -> each XCD's L2 retains
// its A row-panels instead of all 8 XCDs thrashing the same panels.
// MODE 0: bf16 (n0>=2048 tiles transposed to vTout when non-null)
// MODE 1: f32 = acc+res | 2: bf16 = gelu(acc+bias) | 3: f32 = acc+bias+res
// ---------------------------------------------------------------------------
template<int MODE, int K, int N>
__global__ __launch_bounds__(256)
void gemm_bt(const ushort_t* __restrict__ A, const ushort_t* __restrict__ Bt,
             void* __restrict__ Cout, const float* __restrict__ bias,
             const float* __restrict__ res, ushort_t* __restrict__ vTout) {
    constexpr int BK = 64;
    __shared__ __align__(16) ushort_t As[128 * 64];
    __shared__ __align__(16) ushort_t Bs[128 * 64];
    const int tid = threadIdx.x;
    const int wave = tid >> 6, lane = tid & 63;
    const int quad = lane >> 4, l16 = lane & 15;
    // bijective chunked XCD swizzle (all launched grids have nwg % 8 == 0):
    // dispatch order o round-robins XCDs; new id = (o&7)*(nwg/8) + (o>>3)
    // gives XCD c the contiguous id range [c*nwg/8, (c+1)*nwg/8).
    const int nwg = gridDim.x * gridDim.y;
    int id = blockIdx.y * gridDim.x + blockIdx.x;
    id = (id & 7) * (nwg >> 3) + (id >> 3);
    const int m0 = (id / gridDim.x) * 128, n0 = (id % gridDim.x) * 128;
    const int wm = (wave >> 1) * 64, wn = (wave & 1) * 64;

    const int r0 = tid >> 3, pc = tid & 7;
    const int lc = pc ^ (r0 & 7);
    const ushort_t* aSrc = A  + (size_t)(m0 + r0) * K + lc * 8;
    const ushort_t* bSrc = Bt + (size_t)(n0 + r0) * K + lc * 8;
    char* aDst = (char*)As + wave * 1024;
    char* bDst = (char*)Bs + wave * 1024;
    const int swz = l16 & 7;

    f32x4 acc[4][4] = {};

    for (int k0 = 0; k0 < K; k0 += BK) {
        __syncthreads();
        #pragma unroll
        for (int c = 0; c < 4; ++c) {
            gl2lds(aSrc + (size_t)c * 32 * K + k0, aDst + c * 4096);
            gl2lds(bSrc + (size_t)c * 32 * K + k0, bDst + c * 4096);
        }
        __syncthreads();
        #pragma unroll
        for (int ks = 0; ks < 2; ++ks) {
            const int cko = ((ks * 4 + quad) ^ swz) * 8;
            bf16x8 af[4], bfr[4];
            #pragma unroll
            for (int i = 0; i < 4; ++i)
                af[i] = *(const bf16x8*)(&As[(wm + i * 16 + l16) * 64 + cko]);
            #pragma unroll
            for (int j = 0; j < 4; ++j)
                bfr[j] = *(const bf16x8*)(&Bs[(wn + j * 16 + l16) * 64 + cko]);
            #pragma unroll
            for (int i = 0; i < 4; ++i)
                #pragma unroll
                for (int j = 0; j < 4; ++j)
                    acc[i][j] = __builtin_amdgcn_mfma_f32_16x16x32_bf16(
                        af[i], bfr[j], acc[i][j], 0, 0, 0);
        }
    }

    // epilogue: C/D layout col = lane&15, row = quad*4 + reg
    if constexpr (MODE == 0) {
        if (vTout && n0 >= 2048) {
            #pragma unroll
            for (int i = 0; i < 4; ++i) {
                int m = m0 + wm + i * 16 + quad * 4;
                int bb = m >> 11, tq = m & 2047;
                #pragma unroll
                for (int j = 0; j < 4; ++j) {
                    int nn = n0 - 2048 + wn + j * 16 + l16;
                    int h = nn >> 6, d = nn & 63;
                    uint2 pk;
                    pk.x = pack2bf(acc[i][j][0], acc[i][j][1]);
                    pk.y = pack2bf(acc[i][j][2], acc[i][j][3]);
                    *(uint2*)(vTout + ((size_t)(bb * 16 + h) * 64 + d) * 2048 + tq) = pk;
                }
            }
            return;
        }
    }
    float bj[4];
    if constexpr (MODE == 2 || MODE == 3) {
        #pragma unroll
        for (int j = 0; j < 4; ++j) bj[j] = bias[n0 + wn + j * 16 + l16];
    }
    #pragma unroll
    for (int i = 0; i < 4; ++i) {
        #pragma unroll
        for (int j = 0; j < 4; ++j) {
            #pragma unroll
            for (int r = 0; r < 4; ++r) {
                int m = m0 + wm + i * 16 + quad * 4 + r;
                int n = n0 + wn + j * 16 + l16;
                size_t idx = (size_t)m * N + n;
                float v = acc[i][j][r];
                if constexpr (MODE == 0) {
                    ((ushort_t*)Cout)[idx] = f2bf(v);
                } else if constexpr (MODE == 1) {
                    ((float*)Cout)[idx] = v + res[idx];
                } else if constexpr (MODE == 2) {
                    ((ushort_t*)Cout)[idx] = f2bf(fast_gelu(v + bj[j]));
                } else {
                    ((float*)Cout)[idx] = v + bj[j] + res[idx];
                }
            }
        }
    }
}

// ---------------------------------------------------------------------------
// Flash attention, S^T formulation, no max-subtraction, double-buffered K/V,
// in-register P transpose via v_permlane{32,16}_swap_b32 (no P LDS round-trip).
// qkv bf16 [4,2048,3072] (Q pre-scaled by 0.125*log2e), vT [64bh][64d][2048t].
// Round-1 form (best measured ~111 us).
// ---------------------------------------------------------------------------
__global__ __launch_bounds__(256)
void attn_kernel(const ushort_t* __restrict__ qkv, const ushort_t* __restrict__ vT,
                 ushort_t* __restrict__ out) {
    constexpr int T = 2048, C3 = 3072, BQ = 128;
    __shared__ __align__(16) ushort_t Ks[2][64 * 64];   // [key][d], swizzled
    __shared__ __align__(16) ushort_t Vs[2][64 * 64];   // [d][key], swizzled
    const int bh = blockIdx.x, b = bh >> 4, h = bh & 15;
    const int qt = blockIdx.y;
    const int tid = threadIdx.x, wave = tid >> 6, lane = tid & 63;
    const int quad = lane >> 4, l16 = lane & 15;
    const int swz = l16 & 7;

    bf16x8 qf[2][2];
    {
        const ushort_t* Qg = qkv + ((size_t)b * T + qt * BQ + wave * 32) * C3 + h * 64;
        #pragma unroll
        for (int i = 0; i < 2; ++i)
            #pragma unroll
            for (int ks = 0; ks < 2; ++ks)
                qf[i][ks] = *(const bf16x8*)(Qg + (size_t)(i * 16 + l16) * C3 + ks * 32 + quad * 8);
    }
    bf16x8 onesf;
    #pragma unroll
    for (int e = 0; e < 8; ++e) onesf[e] = (short)0x3F80;   // bf16 1.0

    const int r0 = tid >> 3, pc = tid & 7;
    const int lc = pc ^ (r0 & 7);
    const ushort_t* KgB = qkv + (size_t)b * T * C3 + 1024 + h * 64 + (size_t)r0 * C3 + lc * 8;
    const ushort_t* VgB = vT + (size_t)bh * 64 * T + (size_t)r0 * T + lc * 8;
    char* kDst0 = (char*)&Ks[0][0] + wave * 1024;
    char* vDst0 = (char*)&Vs[0][0] + wave * 1024;

    f32x4 o_acc[2][4] = {};
    f32x4 l_acc[2] = {};

    #pragma unroll
    for (int c = 0; c < 2; ++c) {
        gl2lds(KgB + (size_t)c * 32 * C3, kDst0 + c * 4096);
        gl2lds(VgB + (size_t)c * 32 * T,  vDst0 + c * 4096);
    }

    for (int kt = 0; kt < T / 64; ++kt) {
        const int cur = kt & 1;
        __syncthreads();
        if (kt + 1 < T / 64) {
            const int nb = (cur ^ 1) * 8192;
            #pragma unroll
            for (int c = 0; c < 2; ++c) {
                gl2lds(KgB + ((size_t)(kt + 1) * 64 + c * 32) * C3, kDst0 + nb + c * 4096);
                gl2lds(VgB + (size_t)c * 32 * T + (kt + 1) * 64,    vDst0 + nb + c * 4096);
            }
        }
        const ushort_t* Kc = &Ks[cur][0];
        const ushort_t* Vc = &Vs[cur][0];

        f32x4 s[2][4] = {};
        #pragma unroll
        for (int ks = 0; ks < 2; ++ks) {
            const int cko = ((ks * 4 + quad) ^ swz) * 8;
            bf16x8 kf[4];
            #pragma unroll
            for (int j = 0; j < 4; ++j)
                kf[j] = *(const bf16x8*)(&Kc[(j * 16 + l16) * 64 + cko]);
            #pragma unroll
            for (int i = 0; i < 2; ++i)
                #pragma unroll
                for (int j = 0; j < 4; ++j)
                    s[i][j] = __builtin_amdgcn_mfma_f32_16x16x32_bf16(
                        kf[j], qf[i][ks], s[i][j], 0, 0, 0);
        }

        bf16x8 pf[2][2];
        #pragma unroll
        for (int i = 0; i < 2; ++i) {
            unsigned u[4][2];
            #pragma unroll
            for (int j = 0; j < 4; ++j) {
                float p0 = __builtin_amdgcn_exp2f(s[i][j][0]);
                float p1 = __builtin_amdgcn_exp2f(s[i][j][1]);
                float p2 = __builtin_amdgcn_exp2f(s[i][j][2]);
                float p3 = __builtin_amdgcn_exp2f(s[i][j][3]);
                u[j][0] = cvtpk2bf(p0, p1);
                u[j][1] = cvtpk2bf(p2, p3);
            }
            #pragma unroll
            for (int ks2 = 0; ks2 < 2; ++ks2) {
                unsigned d0 = u[2 * ks2][0], d2 = u[2 * ks2 + 1][0];
                asm("v_permlane32_swap_b32 %0, %1\n\t"
                    "v_permlane16_swap_b32 %0, %1" : "+v"(d0), "+v"(d2));
                unsigned d1 = u[2 * ks2][1], d3 = u[2 * ks2 + 1][1];
                asm("v_permlane32_swap_b32 %0, %1\n\t"
                    "v_permlane16_swap_b32 %0, %1" : "+v"(d1), "+v"(d3));
                union { unsigned d[4]; bf16x8 v; } fr;
                fr.d[0] = d0; fr.d[1] = d1; fr.d[2] = d2; fr.d[3] = d3;
                pf[i][ks2] = fr.v;
            }
        }

        #pragma unroll
        for (int ks2 = 0; ks2 < 2; ++ks2) {
            const int cko = ((ks2 * 4 + quad) ^ swz) * 8;
            bf16x8 vf[4];
            #pragma unroll
            for (int j = 0; j < 4; ++j)
                vf[j] = *(const bf16x8*)(&Vc[(j * 16 + l16) * 64 + cko]);
            #pragma unroll
            for (int i = 0; i < 2; ++i) {
                #pragma unroll
                for (int j = 0; j < 4; ++j)
                    o_acc[i][j] = __builtin_amdgcn_mfma_f32_16x16x32_bf16(
                        pf[i][ks2], vf[j], o_acc[i][j], 0, 0, 0);
                l_acc[i] = __builtin_amdgcn_mfma_f32_16x16x32_bf16(
                    pf[i][ks2], onesf, l_acc[i], 0, 0, 0);
            }
        }
    }

    #pragma unroll
    for (int i = 0; i < 2; ++i) {
        #pragma unroll
        for (int r = 0; r < 4; ++r) {
            float inv = 1.0f / l_acc[i][r];
            int row = qt * BQ + wave * 32 + i * 16 + quad * 4 + r;
            size_t orow = ((size_t)b * T + row) * 1024 + h * 64;
            #pragma unroll
            for (int j = 0; j < 4; ++j)
                out[orow + j * 16 + l16] = f2bf(o_acc[i][j][r] * inv);
        }
    }
}

// ---------------------------------------------------------------------------
extern "C" void kernel_launch(void* const* d_in, const int* in_sizes, int n_in,
                              void* d_out, int out_size, void* d_ws, size_t ws_size,
                              hipStream_t stream) {
    const float* x     = (const float*)d_in[0];
    const float* ln1g  = (const float*)d_in[1];
    const float* ln1b  = (const float*)d_in[2];
    const float* ln2g  = (const float*)d_in[3];
    const float* ln2b  = (const float*)d_in[4];
    const float* wqkv  = (const float*)d_in[5];
    const float* wproj = (const float*)d_in[6];
    const float* w1    = (const float*)d_in[7];
    const float* b1    = (const float*)d_in[8];
    const float* w2    = (const float*)d_in[9];
    const float* b2    = (const float*)d_in[10];
    float* out = (float*)d_out;

    const size_t MT = 8192;  // B*T
    ushort_t* wqkvT  = (ushort_t*)d_ws;              // [3072][1024]
    ushort_t* wprojT = wqkvT  + (size_t)3072 * 1024; // [1024][1024]
    ushort_t* w1T    = wprojT + (size_t)1024 * 1024; // [4096][1024]
    ushort_t* w2T    = w1T    + (size_t)4096 * 1024; // [1024][4096]
    ushort_t* xn     = w2T    + (size_t)1024 * 4096; // [8192][1024] bf16
    ushort_t* qkvb   = xn     + MT * 1024;           // [8192][3072] bf16 (V part unused)
    ushort_t* attnb  = qkvb   + MT * 3072;           // [8192][1024] bf16
    float*    x2     = (float*)(attnb + MT * 1024);  // [8192][1024] f32
    ushort_t* xn2    = (ushort_t*)(x2 + MT * 1024);  // [8192][1024] bf16
    ushort_t* h1     = xn;                 // reuse xn+qkvb (both dead): [8192][4096]
    ushort_t* vT     = (ushort_t*)x2;      // reuse x2 region pre-proj: [64][64][2048]

    dim3 blk256(256);
    dim3 tblk(32, 8);
    const float qscale = 0.125f * 1.4426950408889634f;  // score scale * log2(e), folded into Q

    tcast_all<<<dim3(12288), tblk, 0, stream>>>(wqkv, wproj, w1, w2,
                                                wqkvT, wprojT, w1T, w2T, qscale);

    ln_kernel<<<dim3(8192), blk256, 0, stream>>>(x, ln1g, ln1b, xn);
    gemm_bt<0, 1024, 3072><<<dim3(24, 64), blk256, 0, stream>>>(xn, wqkvT, qkvb, nullptr, nullptr, vT);
    attn_kernel<<<dim3(64, 16), blk256, 0, stream>>>(qkvb, vT, attnb);
    gemm_bt<1, 1024, 1024><<<dim3(8, 64), blk256, 0, stream>>>(attnb, wprojT, x2, nullptr, x, nullptr);
    ln_kernel<<<dim3(8192), blk256, 0, stream>>>(x2, ln2g, ln2b, xn2);
    gemm_bt<2, 1024, 4096><<<dim3(32, 64), blk256, 0, stream>>>(xn2, w1T, h1, b1, nullptr, nullptr);
    gemm_bt<3, 4096, 1024><<<dim3(8, 64), blk256, 0, stream>>>(h1, w2T, out, b2, x2, nullptr);
}

// Round 8
// 479.190 us; speedup vs baseline: 1.1226x; 1.0144x over previous
//
#include <hip/hip_runtime.h>
#include <hip/hip_bf16.h>
#include <math.h>

typedef __attribute__((ext_vector_type(8))) short bf16x8;   // 8 bf16 in 4 VGPRs
typedef __attribute__((ext_vector_type(4))) float f32x4;    // MFMA C/D frag
typedef unsigned short ushort_t;

__device__ __forceinline__ ushort_t f2bf(float f) {
    union { float f; unsigned u; } v; v.f = f;
    unsigned r = v.u + 0x7FFF + ((v.u >> 16) & 1);   // RNE
    return (ushort_t)(r >> 16);
}

// pack two f32 -> 2 bf16 (round-half-up): 2 adds + 1 v_perm; a in low half
__device__ __forceinline__ unsigned pack2bf(float a, float b) {
    union { float f; unsigned u; } x, y; x.f = a; y.f = b;
    return __builtin_amdgcn_perm(y.u + 0x8000u, x.u + 0x8000u, 0x07060302u);
}

// single-instruction pair pack (RNE), a in low half
__device__ __forceinline__ unsigned cvtpk2bf(float a, float b) {
    unsigned r;
    asm("v_cvt_pk_bf16_f32 %0, %1, %2" : "=v"(r) : "v"(a), "v"(b));
    return r;
}

// async 16B global -> LDS (wave-uniform LDS base; lane data lands at base+lane*16)
__device__ __forceinline__ void gl2lds(const void* g, void* l) {
    __builtin_amdgcn_global_load_lds(
        (const __attribute__((address_space(1))) void*)g,
        (__attribute__((address_space(3))) void*)l, 16, 0, 0);
}

// fast GELU (tanh form via sigmoid): max |err| vs erf-GELU ~1e-3
__device__ __forceinline__ float fast_gelu(float tt) {
    float t2 = tt * tt;
    float arg = tt * fmaf(0.07135481283f, t2, 1.595769122f);
    float e = __builtin_amdgcn_exp2f(arg * -1.442695041f);
    return tt * __builtin_amdgcn_rcpf(1.0f + e);
}

// ---------------------------------------------------------------------------
// Merged transpose+cast for all 4 weights (one launch).
// ---------------------------------------------------------------------------
__global__ __launch_bounds__(256)
void tcast_all(const float* __restrict__ wqkv, const float* __restrict__ wproj,
               const float* __restrict__ w1, const float* __restrict__ w2,
               ushort_t* __restrict__ wqkvT, ushort_t* __restrict__ wprojT,
               ushort_t* __restrict__ w1T, ushort_t* __restrict__ w2T,
               float qscale) {
    __shared__ float tile[32][33];
    int id = blockIdx.x;
    const float* in; ushort_t* out; int R, Cc, gx, scale_n;
    if (id < 3072)      { in = wqkv;  out = wqkvT;  R = 1024; Cc = 3072; gx = 96;  scale_n = 1024; }
    else if (id < 4096) { id -= 3072; in = wproj; out = wprojT; R = 1024; Cc = 1024; gx = 32; scale_n = 0; }
    else if (id < 8192) { id -= 4096; in = w1;    out = w1T;    R = 1024; Cc = 4096; gx = 128; scale_n = 0; }
    else                { id -= 8192; in = w2;    out = w2T;    R = 4096; Cc = 1024; gx = 32; scale_n = 0; }
    int bc = (id % gx) * 32, br = (id / gx) * 32;
    int tx = threadIdx.x, ty = threadIdx.y;
    #pragma unroll
    for (int i = 0; i < 32; i += 8)
        tile[ty + i][tx] = in[(size_t)(br + ty + i) * Cc + bc + tx];
    __syncthreads();
    #pragma unroll
    for (int i = 0; i < 32; i += 8) {
        int n = bc + ty + i;
        float v = tile[tx][ty + i];
        if (n < scale_n) v *= qscale;
        out[(size_t)n * R + br + tx] = f2bf(v);
    }
}

// ---------------------------------------------------------------------------
// LayerNorm over rows of 1024, fp32 in -> bf16 out. One block (256) per row.
// ---------------------------------------------------------------------------
__global__ __launch_bounds__(256)
void ln_kernel(const float* __restrict__ x, const float* __restrict__ g,
               const float* __restrict__ b, ushort_t* __restrict__ out) {
    const int row = blockIdx.x;
    const int t = threadIdx.x;
    const float4 xv = ((const float4*)(x + (size_t)row * 1024))[t];
    float s  = xv.x + xv.y + xv.z + xv.w;
    float ss = xv.x*xv.x + xv.y*xv.y + xv.z*xv.z + xv.w*xv.w;
    #pragma unroll
    for (int off = 32; off > 0; off >>= 1) {
        s  += __shfl_xor(s, off);
        ss += __shfl_xor(ss, off);
    }
    __shared__ float red[8];
    int wave = t >> 6, lane = t & 63;
    if (lane == 0) { red[wave] = s; red[4 + wave] = ss; }
    __syncthreads();
    s  = red[0] + red[1] + red[2] + red[3];
    ss = red[4] + red[5] + red[6] + red[7];
    float mu  = s * (1.0f / 1024.0f);
    float var = ss * (1.0f / 1024.0f) - mu * mu;
    float rstd = rsqrtf(var + 1e-5f);
    float4 gv = ((const float4*)g)[t];
    float4 bv = ((const float4*)b)[t];
    ushort4 o;
    o.x = f2bf((xv.x - mu) * rstd * gv.x + bv.x);
    o.y = f2bf((xv.y - mu) * rstd * gv.y + bv.y);
    o.z = f2bf((xv.z - mu) * rstd * gv.z + bv.z);
    o.w = f2bf((xv.w - mu) * rstd * gv.w + bv.w);
    ((ushort4*)(out + (size_t)row * 1024))[t] = o;
}

// ---------------------------------------------------------------------------
// GEMM: C[M,N] = A[M,K] * Bt[N,K], bf16 in, fp32 acc. 128x128 tile, BK=64.
// XOR-swizzled LDS (chunk ^= row&7) applied at the GLOBAL source address.
// Two-level locality remap:
//  L1 (XCD): bijective chunked swizzle — XCD c owns ids [c*nwg/8,(c+1)*nwg/8).
//  L2 (cache): within the chunk, iterate in 4m x 8n SUB-TILES so the
//  co-temporal working set (A 4 row-panels + B 8 col-panels) fits the 4 MB
//  per-XCD L2 (ff1: 4 MB, qkv: 3 MB vs 12 MB with n-fastest order).
//  Requires gridDim.x % 8 == 0 and gridDim.y % 8 == 0 (all launches comply).
// MODE 0: bf16 (n0>=2048 tiles transposed to vTout when non-null)
// MODE 1: f32 = acc+res | 2: bf16 = gelu(acc+bias) | 3: f32 = acc+bias+res
// ---------------------------------------------------------------------------
template<int MODE, int K, int N>
__global__ __launch_bounds__(256)
void gemm_bt(const ushort_t* __restrict__ A, const ushort_t* __restrict__ Bt,
             void* __restrict__ Cout, const float* __restrict__ bias,
             const float* __restrict__ res, ushort_t* __restrict__ vTout) {
    constexpr int BK = 64;
    __shared__ __align__(16) ushort_t As[128 * 64];
    __shared__ __align__(16) ushort_t Bs[128 * 64];
    const int tid = threadIdx.x;
    const int wave = tid >> 6, lane = tid & 63;
    const int quad = lane >> 4, l16 = lane & 15;
    // ---- two-level locality remap ----
    const int gx = gridDim.x;
    const int nwg = gx * gridDim.y;
    const int oid = blockIdx.y * gx + blockIdx.x;
    const int chunkSize = nwg >> 3;            // ids per XCD
    const int xcd = oid & 7;                   // HW round-robins linear id % 8
    const int lid = oid >> 3;                  // position inside XCD chunk
    const int band = lid / (gx << 2);          // 4-m-row band (4*gx ids each)
    int rem = lid - band * (gx << 2);
    const int ng = rem >> 5;                   // 8-n group (32 ids each)
    rem &= 31;
    const int mrow = (chunkSize / gx) * xcd + (band << 2) + (rem >> 3);
    const int ncol = (ng << 3) + (rem & 7);
    const int m0 = mrow * 128, n0 = ncol * 128;
    // ----------------------------------
    const int wm = (wave >> 1) * 64, wn = (wave & 1) * 64;

    const int r0 = tid >> 3, pc = tid & 7;
    const int lc = pc ^ (r0 & 7);
    const ushort_t* aSrc = A  + (size_t)(m0 + r0) * K + lc * 8;
    const ushort_t* bSrc = Bt + (size_t)(n0 + r0) * K + lc * 8;
    char* aDst = (char*)As + wave * 1024;
    char* bDst = (char*)Bs + wave * 1024;
    const int swz = l16 & 7;

    f32x4 acc[4][4] = {};

    for (int k0 = 0; k0 < K; k0 += BK) {
        __syncthreads();
        #pragma unroll
        for (int c = 0; c < 4; ++c) {
            gl2lds(aSrc + (size_t)c * 32 * K + k0, aDst + c * 4096);
            gl2lds(bSrc + (size_t)c * 32 * K + k0, bDst + c * 4096);
        }
        __syncthreads();
        #pragma unroll
        for (int ks = 0; ks < 2; ++ks) {
            const int cko = ((ks * 4 + quad) ^ swz) * 8;
            bf16x8 af[4], bfr[4];
            #pragma unroll
            for (int i = 0; i < 4; ++i)
                af[i] = *(const bf16x8*)(&As[(wm + i * 16 + l16) * 64 + cko]);
            #pragma unroll
            for (int j = 0; j < 4; ++j)
                bfr[j] = *(const bf16x8*)(&Bs[(wn + j * 16 + l16) * 64 + cko]);
            #pragma unroll
            for (int i = 0; i < 4; ++i)
                #pragma unroll
                for (int j = 0; j < 4; ++j)
                    acc[i][j] = __builtin_amdgcn_mfma_f32_16x16x32_bf16(
                        af[i], bfr[j], acc[i][j], 0, 0, 0);
        }
    }

    // epilogue: C/D layout col = lane&15, row = quad*4 + reg
    if constexpr (MODE == 0) {
        if (vTout && n0 >= 2048) {
            #pragma unroll
            for (int i = 0; i < 4; ++i) {
                int m = m0 + wm + i * 16 + quad * 4;
                int bb = m >> 11, tq = m & 2047;
                #pragma unroll
                for (int j = 0; j < 4; ++j) {
                    int nn = n0 - 2048 + wn + j * 16 + l16;
                    int h = nn >> 6, d = nn & 63;
                    uint2 pk;
                    pk.x = pack2bf(acc[i][j][0], acc[i][j][1]);
                    pk.y = pack2bf(acc[i][j][2], acc[i][j][3]);
                    *(uint2*)(vTout + ((size_t)(bb * 16 + h) * 64 + d) * 2048 + tq) = pk;
                }
            }
            return;
        }
    }
    float bj[4];
    if constexpr (MODE == 2 || MODE == 3) {
        #pragma unroll
        for (int j = 0; j < 4; ++j) bj[j] = bias[n0 + wn + j * 16 + l16];
    }
    #pragma unroll
    for (int i = 0; i < 4; ++i) {
        #pragma unroll
        for (int j = 0; j < 4; ++j) {
            #pragma unroll
            for (int r = 0; r < 4; ++r) {
                int m = m0 + wm + i * 16 + quad * 4 + r;
                int n = n0 + wn + j * 16 + l16;
                size_t idx = (size_t)m * N + n;
                float v = acc[i][j][r];
                if constexpr (MODE == 0) {
                    ((ushort_t*)Cout)[idx] = f2bf(v);
                } else if constexpr (MODE == 1) {
                    ((float*)Cout)[idx] = v + res[idx];
                } else if constexpr (MODE == 2) {
                    ((ushort_t*)Cout)[idx] = f2bf(fast_gelu(v + bj[j]));
                } else {
                    ((float*)Cout)[idx] = v + bj[j] + res[idx];
                }
            }
        }
    }
}

// ---------------------------------------------------------------------------
// Flash attention, S^T formulation, no max-subtraction, double-buffered K/V,
// in-register P transpose via v_permlane{32,16}_swap_b32 (no P LDS round-trip).
// qkv bf16 [4,2048,3072] (Q pre-scaled by 0.125*log2e), vT [64bh][64d][2048t].
// Round-1 form (best measured ~108 us).
// ---------------------------------------------------------------------------
__global__ __launch_bounds__(256)
void attn_kernel(const ushort_t* __restrict__ qkv, const ushort_t* __restrict__ vT,
                 ushort_t* __restrict__ out) {
    constexpr int T = 2048, C3 = 3072, BQ = 128;
    __shared__ __align__(16) ushort_t Ks[2][64 * 64];   // [key][d], swizzled
    __shared__ __align__(16) ushort_t Vs[2][64 * 64];   // [d][key], swizzled
    const int bh = blockIdx.x, b = bh >> 4, h = bh & 15;
    const int qt = blockIdx.y;
    const int tid = threadIdx.x, wave = tid >> 6, lane = tid & 63;
    const int quad = lane >> 4, l16 = lane & 15;
    const int swz = l16 & 7;

    bf16x8 qf[2][2];
    {
        const ushort_t* Qg = qkv + ((size_t)b * T + qt * BQ + wave * 32) * C3 + h * 64;
        #pragma unroll
        for (int i = 0; i < 2; ++i)
            #pragma unroll
            for (int ks = 0; ks < 2; ++ks)
                qf[i][ks] = *(const bf16x8*)(Qg + (size_t)(i * 16 + l16) * C3 + ks * 32 + quad * 8);
    }
    bf16x8 onesf;
    #pragma unroll
    for (int e = 0; e < 8; ++e) onesf[e] = (short)0x3F80;   // bf16 1.0

    const int r0 = tid >> 3, pc = tid & 7;
    const int lc = pc ^ (r0 & 7);
    const ushort_t* KgB = qkv + (size_t)b * T * C3 + 1024 + h * 64 + (size_t)r0 * C3 + lc * 8;
    const ushort_t* VgB = vT + (size_t)bh * 64 * T + (size_t)r0 * T + lc * 8;
    char* kDst0 = (char*)&Ks[0][0] + wave * 1024;
    char* vDst0 = (char*)&Vs[0][0] + wave * 1024;

    f32x4 o_acc[2][4] = {};
    f32x4 l_acc[2] = {};

    #pragma unroll
    for (int c = 0; c < 2; ++c) {
        gl2lds(KgB + (size_t)c * 32 * C3, kDst0 + c * 4096);
        gl2lds(VgB + (size_t)c * 32 * T,  vDst0 + c * 4096);
    }

    for (int kt = 0; kt < T / 64; ++kt) {
        const int cur = kt & 1;
        __syncthreads();
        if (kt + 1 < T / 64) {
            const int nb = (cur ^ 1) * 8192;
            #pragma unroll
            for (int c = 0; c < 2; ++c) {
                gl2lds(KgB + ((size_t)(kt + 1) * 64 + c * 32) * C3, kDst0 + nb + c * 4096);
                gl2lds(VgB + (size_t)c * 32 * T + (kt + 1) * 64,    vDst0 + nb + c * 4096);
            }
        }
        const ushort_t* Kc = &Ks[cur][0];
        const ushort_t* Vc = &Vs[cur][0];

        f32x4 s[2][4] = {};
        #pragma unroll
        for (int ks = 0; ks < 2; ++ks) {
            const int cko = ((ks * 4 + quad) ^ swz) * 8;
            bf16x8 kf[4];
            #pragma unroll
            for (int j = 0; j < 4; ++j)
                kf[j] = *(const bf16x8*)(&Kc[(j * 16 + l16) * 64 + cko]);
            #pragma unroll
            for (int i = 0; i < 2; ++i)
                #pragma unroll
                for (int j = 0; j < 4; ++j)
                    s[i][j] = __builtin_amdgcn_mfma_f32_16x16x32_bf16(
                        kf[j], qf[i][ks], s[i][j], 0, 0, 0);
        }

        bf16x8 pf[2][2];
        #pragma unroll
        for (int i = 0; i < 2; ++i) {
            unsigned u[4][2];
            #pragma unroll
            for (int j = 0; j < 4; ++j) {
                float p0 = __builtin_amdgcn_exp2f(s[i][j][0]);
                float p1 = __builtin_amdgcn_exp2f(s[i][j][1]);
                float p2 = __builtin_amdgcn_exp2f(s[i][j][2]);
                float p3 = __builtin_amdgcn_exp2f(s[i][j][3]);
                u[j][0] = cvtpk2bf(p0, p1);
                u[j][1] = cvtpk2bf(p2, p3);
            }
            #pragma unroll
            for (int ks2 = 0; ks2 < 2; ++ks2) {
                unsigned d0 = u[2 * ks2][0], d2 = u[2 * ks2 + 1][0];
                asm("v_permlane32_swap_b32 %0, %1\n\t"
                    "v_permlane16_swap_b32 %0, %1" : "+v"(d0), "+v"(d2));
                unsigned d1 = u[2 * ks2][1], d3 = u[2 * ks2 + 1][1];
                asm("v_permlane32_swap_b32 %0, %1\n\t"
                    "v_permlane16_swap_b32 %0, %1" : "+v"(d1), "+v"(d3));
                union { unsigned d[4]; bf16x8 v; } fr;
                fr.d[0] = d0; fr.d[1] = d1; fr.d[2] = d2; fr.d[3] = d3;
                pf[i][ks2] = fr.v;
            }
        }

        #pragma unroll
        for (int ks2 = 0; ks2 < 2; ++ks2) {
            const int cko = ((ks2 * 4 + quad) ^ swz) * 8;
            bf16x8 vf[4];
            #pragma unroll
            for (int j = 0; j < 4; ++j)
                vf[j] = *(const bf16x8*)(&Vc[(j * 16 + l16) * 64 + cko]);
            #pragma unroll
            for (int i = 0; i < 2; ++i) {
                #pragma unroll
                for (int j = 0; j < 4; ++j)
                    o_acc[i][j] = __builtin_amdgcn_mfma_f32_16x16x32_bf16(
                        pf[i][ks2], vf[j], o_acc[i][j], 0, 0, 0);
                l_acc[i] = __builtin_amdgcn_mfma_f32_16x16x32_bf16(
                    pf[i][ks2], onesf, l_acc[i], 0, 0, 0);
            }
        }
    }

    #pragma unroll
    for (int i = 0; i < 2; ++i) {
        #pragma unroll
        for (int r = 0; r < 4; ++r) {
            float inv = 1.0f / l_acc[i][r];
            int row = qt * BQ + wave * 32 + i * 16 + quad * 4 + r;
            size_t orow = ((size_t)b * T + row) * 1024 + h * 64;
            #pragma unroll
            for (int j = 0; j < 4; ++j)
                out[orow + j * 16 + l16] = f2bf(o_acc[i][j][r] * inv);
        }
    }
}

// ---------------------------------------------------------------------------
extern "C" void kernel_launch(void* const* d_in, const int* in_sizes, int n_in,
                              void* d_out, int out_size, void* d_ws, size_t ws_size,
                              hipStream_t stream) {
    const float* x     = (const float*)d_in[0];
    const float* ln1g  = (const float*)d_in[1];
    const float* ln1b  = (const float*)d_in[2];
    const float* ln2g  = (const float*)d_in[3];
    const float* ln2b  = (const float*)d_in[4];
    const float* wqkv  = (const float*)d_in[5];
    const float* wproj = (const float*)d_in[6];
    const float* w1    = (const float*)d_in[7];
    const float* b1    = (const float*)d_in[8];
    const float* w2    = (const float*)d_in[9];
    const float* b2    = (const float*)d_in[10];
    float* out = (float*)d_out;

    const size_t MT = 8192;  // B*T
    ushort_t* wqkvT  = (ushort_t*)d_ws;              // [3072][1024]
    ushort_t* wprojT = wqkvT  + (size_t)3072 * 1024; // [1024][1024]
    ushort_t* w1T    = wprojT + (size_t)1024 * 1024; // [4096][1024]
    ushort_t* w2T    = w1T    + (size_t)4096 * 1024; // [1024][4096]
    ushort_t* xn     = w2T    + (size_t)1024 * 4096; // [8192][1024] bf16
    ushort_t* qkvb   = xn     + MT * 1024;           // [8192][3072] bf16 (V part unused)
    ushort_t* attnb  = qkvb   + MT * 3072;           // [8192][1024] bf16
    float*    x2     = (float*)(attnb + MT * 1024);  // [8192][1024] f32
    ushort_t* xn2    = (ushort_t*)(x2 + MT * 1024);  // [8192][1024] bf16
    ushort_t* h1     = xn;                 // reuse xn+qkvb (both dead): [8192][4096]
    ushort_t* vT     = (ushort_t*)x2;      // reuse x2 region pre-proj: [64][64][2048]

    dim3 blk256(256);
    dim3 tblk(32, 8);
    const float qscale = 0.125f * 1.4426950408889634f;  // score scale * log2(e), folded into Q

    tcast_all<<<dim3(12288), tblk, 0, stream>>>(wqkv, wproj, w1, w2,
                                                wqkvT, wprojT, w1T, w2T, qscale);

    ln_kernel<<<dim3(8192), blk256, 0, stream>>>(x, ln1g, ln1b, xn);
    gemm_bt<0, 1024, 3072><<<dim3(24, 64), blk256, 0, stream>>>(xn, wqkvT, qkvb, nullptr, nullptr, vT);
    attn_kernel<<<dim3(64, 16), blk256, 0, stream>>>(qkvb, vT, attnb);
    gemm_bt<1, 1024, 1024><<<dim3(8, 64), blk256, 0, stream>>>(attnb, wprojT, x2, nullptr, x, nullptr);
    ln_kernel<<<dim3(8192), blk256, 0, stream>>>(x2, ln2g, ln2b, xn2);
    gemm_bt<2, 1024, 4096><<<dim3(32, 64), blk256, 0, stream>>>(xn2, w1T, h1, b1, nullptr, nullptr);
    gemm_bt<3, 4096, 1024><<<dim3(8, 64), blk256, 0, stream>>>(h1, w2T, out, b2, x2, nullptr);
}